// Round 2
// baseline (1368.935 us; speedup 1.0000x reference)
//
#include <hip/hip_runtime.h>

#define N_NODES 50000
#define N_EDGES 800000
#define ET (N_EDGES + N_NODES)   // 850000 incl. self loops
#define HEADS 8
#define NPAD 50048               // 782 blocks * 64 nodes

// ---------- edge-index layout detection (int32 vs int64 storage) ----------
__global__ void k_detect(const int* __restrict__ ei, int* __restrict__ flag){
  if (blockIdx.x == 0 && threadIdx.x == 0){
    int zeros = 0;
    for (int i = 0; i < 64; i++){
      if (ei[2*i + 1] == 0) zeros++;
    }
    *flag = (zeros >= 60) ? 1 : 0;   // 1 => int64 little-endian layout
  }
}

__device__ __forceinline__ int edge_src(const int* ei, int e, int is64){
  if (e >= N_EDGES) return e - N_EDGES;          // self loop
  return is64 ? ei[2*e] : ei[e];
}
__device__ __forceinline__ int edge_dst(const int* ei, int e, int is64){
  if (e >= N_EDGES) return e - N_EDGES;          // self loop
  return is64 ? ei[2*(N_EDGES + e)] : ei[N_EDGES + e];
}

// ---------------- CSR build ----------------
__global__ void k_zero2(int* __restrict__ a, int* __restrict__ b, int n){
  int i = blockIdx.x*blockDim.x + threadIdx.x;
  if (i < n){ a[i] = 0; b[i] = 0; }
}

__global__ void k_degree(const int* __restrict__ ei, int* __restrict__ deg,
                         const int* __restrict__ flag){
  int e = blockIdx.x*blockDim.x + threadIdx.x;
  if (e >= ET) return;
  int is64 = *flag;
  int d = edge_dst(ei, e, is64);
  atomicAdd(&deg[d], 1);
}

__global__ void k_scan(const int* __restrict__ deg, int* __restrict__ row_ptr){
  __shared__ int lds[1024];
  __shared__ int carry_s;
  if (threadIdx.x == 0) carry_s = 0;
  __syncthreads();
  for (int base = 0; base < N_NODES; base += 1024){
    int i = base + threadIdx.x;
    int v = (i < N_NODES) ? deg[i] : 0;
    lds[threadIdx.x] = v;
    __syncthreads();
    for (int off = 1; off < 1024; off <<= 1){
      int t = (threadIdx.x >= off) ? lds[threadIdx.x - off] : 0;
      __syncthreads();
      lds[threadIdx.x] += t;
      __syncthreads();
    }
    int carry = carry_s;
    if (i < N_NODES) row_ptr[i] = carry + lds[threadIdx.x] - v;  // exclusive
    __syncthreads();
    if (threadIdx.x == 1023) carry_s = carry + lds[1023];
    __syncthreads();
  }
  if (threadIdx.x == 0) row_ptr[N_NODES] = carry_s;
}

__global__ void k_fill(const int* __restrict__ ei, const int* __restrict__ row_ptr,
                       int* __restrict__ cnt, int* __restrict__ col,
                       const int* __restrict__ flag){
  int e = blockIdx.x*blockDim.x + threadIdx.x;
  if (e >= ET) return;
  int is64 = *flag;
  int s = edge_src(ei, e, is64);
  int d = edge_dst(ei, e, is64);
  int pos = atomicAdd(&cnt[d], 1);
  col[row_ptr[d] + pos] = s;
}

// ---------------- weight prep for layer 2 ----------------
// wtilde[k,h] = sum_d W2[k, h*64+d] * att[h,d]   (fold W2 into attention vecs)
__global__ void k_wtilde(const float* __restrict__ W2, const float* __restrict__ as2,
                         const float* __restrict__ ad2,
                         float* __restrict__ ws2, float* __restrict__ wd2){
  int t = blockIdx.x*blockDim.x + threadIdx.x;
  if (t >= 1024) return;
  int k = t >> 3, h = t & 7;
  float s = 0.f, d = 0.f;
  for (int dd = 0; dd < 64; dd++){
    float w = W2[k*512 + h*64 + dd];
    s += w * as2[h*64 + dd];
    d += w * ad2[h*64 + dd];
  }
  ws2[k*8 + h] = s;
  wd2[k*8 + h] = d;
}

// Wt[(h*128+k)*64 + c] = 0.125 * W2[k, h*64+c]   (fold head-mean)
__global__ void k_w2t(const float* __restrict__ W2, float* __restrict__ Wt){
  int t = blockIdx.x*blockDim.x + threadIdx.x;
  if (t >= 65536) return;
  int row = t >> 6, c = t & 63;
  int h = row >> 7, k = row & 127;
  Wt[t] = 0.125f * W2[k*512 + h*64 + c];
}

// ---------------- layer 1: GEMM [N,128]x[128,128] + alpha_src/dst ----------------
__global__ void k_gemm_alpha1(const float* __restrict__ x, const float* __restrict__ W,
                              const float* __restrict__ asv, const float* __restrict__ adv,
                              float* __restrict__ h, float* __restrict__ als,
                              float* __restrict__ ald){
  __shared__ float xs[8][128];
  int c = threadIdx.x;           // 0..127 (output column)
  int n0 = blockIdx.x * 8;
  #pragma unroll
  for (int i = 0; i < 8; i++){
    int n = n0 + i;
    xs[i][c] = (n < N_NODES) ? x[n*128 + c] : 0.f;
  }
  __syncthreads();
  float acc[8] = {0.f,0.f,0.f,0.f,0.f,0.f,0.f,0.f};
  for (int k = 0; k < 128; k++){
    float w = W[k*128 + c];
    #pragma unroll
    for (int i = 0; i < 8; i++) acc[i] += xs[i][k] * w;
  }
  float a_s = asv[c], a_d = adv[c];   // flat [8,16] -> index c
  #pragma unroll
  for (int i = 0; i < 8; i++){
    int n = n0 + i;
    if (n >= N_NODES) break;          // block-uniform
    h[n*128 + c] = acc[i];
    float vs = acc[i] * a_s;
    float vd = acc[i] * a_d;
    #pragma unroll
    for (int off = 1; off < 16; off <<= 1){
      vs += __shfl_xor(vs, off, 64);
      vd += __shfl_xor(vd, off, 64);
    }
    if ((c & 15) == 0){
      als[n*8 + (c >> 4)] = vs;
      ald[n*8 + (c >> 4)] = vd;
    }
  }
}

// ---------------- edge softmax weights (one wave per dst node) ----------------
__global__ void k_attn(const float* __restrict__ als, const float* __restrict__ ald,
                       const int* __restrict__ row_ptr, const int* __restrict__ col,
                       float* __restrict__ ew){
  int gid = blockIdx.x*blockDim.x + threadIdx.x;
  int n = gid >> 6;
  int lane = threadIdx.x & 63;
  if (n >= N_NODES) return;
  int beg = row_ptr[n], end = row_ptr[n+1];
  int items = (end - beg) * 8;        // (edge, head) pairs
  int h = lane & 7;                   // fixed head class per lane
  float ad = ald[n*8 + h];
  float m = -1e30f;
  for (int it = lane; it < items; it += 64){
    int s = col[beg + (it >> 3)];
    float a = als[s*8 + h] + ad;
    float e = (a > 0.f) ? a : 0.2f*a;
    m = fmaxf(m, e);
  }
  m = fmaxf(m, __shfl_xor(m, 8, 64));
  m = fmaxf(m, __shfl_xor(m, 16, 64));
  m = fmaxf(m, __shfl_xor(m, 32, 64));
  float den = 0.f;
  for (int it = lane; it < items; it += 64){
    int s = col[beg + (it >> 3)];
    float a = als[s*8 + h] + ad;
    float e = (a > 0.f) ? a : 0.2f*a;
    den += __expf(e - m);
  }
  den += __shfl_xor(den, 8, 64);
  den += __shfl_xor(den, 16, 64);
  den += __shfl_xor(den, 32, 64);
  float inv = 1.f / (den + 1e-16f);
  for (int it = lane; it < items; it += 64){
    int j = beg + (it >> 3);
    int s = col[j];
    float a = als[s*8 + h] + ad;
    float e = (a > 0.f) ? a : 0.2f*a;
    ew[(size_t)j*8 + h] = __expf(e - m) * inv;
  }
}

// ------- layer-1 aggregation: concat heads, +b1, relu, + layer-2 logits -------
__global__ void k_agg1(const float* __restrict__ h, const float* __restrict__ ew,
                       const int* __restrict__ row_ptr, const int* __restrict__ col,
                       const float* __restrict__ bias, float* __restrict__ outp,
                       const float* __restrict__ ws2, const float* __restrict__ wd2,
                       float* __restrict__ als2, float* __restrict__ ald2){
  int gid = blockIdx.x*blockDim.x + threadIdx.x;
  int n = gid >> 6;
  int lane = threadIdx.x & 63;
  if (n >= N_NODES) return;
  int beg = row_ptr[n], end = row_ptr[n+1];
  int c0 = lane, c1 = lane + 64;
  int h0 = c0 >> 4, h1c = c1 >> 4;
  float acc0 = 0.f, acc1 = 0.f;
  for (int j = beg; j < end; j++){
    int s = col[j];
    float w0 = ew[(size_t)j*8 + h0];
    float w1 = ew[(size_t)j*8 + h1c];
    acc0 += w0 * h[s*128 + c0];
    acc1 += w1 * h[s*128 + c1];
  }
  float o0 = acc0 + bias[c0];
  float o1 = acc1 + bias[c1];
  o0 = o0 > 0.f ? o0 : 0.f;
  o1 = o1 > 0.f ? o1 : 0.f;
  outp[n*128 + c0] = o0;
  outp[n*128 + c1] = o1;
  // epilogue: layer-2 attention logits als2/ald2 = hr . wtilde
  #pragma unroll
  for (int hh = 0; hh < 8; hh++){
    float vs = o0*ws2[c0*8 + hh] + o1*ws2[c1*8 + hh];
    float vd = o0*wd2[c0*8 + hh] + o1*wd2[c1*8 + hh];
    #pragma unroll
    for (int off = 1; off < 64; off <<= 1){
      vs += __shfl_xor(vs, off, 64);
      vd += __shfl_xor(vd, off, 64);
    }
    if (lane == 0){
      als2[n*8 + hh] = vs;
      ald2[n*8 + hh] = vd;
    }
  }
}

// ------- layer-2 gather: per-head weighted sums of hr (128-wide) -------
// agg[n, h_local*128 + dim], HG heads starting at hoff
template<int HG>
__global__ void k_agg2n(const float* __restrict__ hr, const float* __restrict__ ew,
                        const int* __restrict__ row_ptr, const int* __restrict__ col,
                        float* __restrict__ agg, int hoff){
  int gid = blockIdx.x*blockDim.x + threadIdx.x;
  int n = gid >> 6;
  int lane = threadIdx.x & 63;
  if (n >= N_NODES) return;
  int beg = row_ptr[n], end = row_ptr[n+1];
  const float2* hr2 = (const float2*)hr;
  float accx[HG], accy[HG];
  #pragma unroll
  for (int i = 0; i < HG; i++){ accx[i] = 0.f; accy[i] = 0.f; }
  for (int j = beg; j < end; j++){
    int s = col[j];
    float2 v = hr2[(size_t)s*64 + lane];
    const float* wp = ew + (size_t)j*8 + hoff;
    float4 wa = *(const float4*)wp;
    float w[HG > 4 ? 8 : 4];
    w[0] = wa.x; w[1] = wa.y; w[2] = wa.z; w[3] = wa.w;
    if (HG == 8){
      float4 wb = *(const float4*)(wp + 4);
      w[4] = wb.x; w[5] = wb.y; w[6] = wb.z; w[7] = wb.w;
    }
    #pragma unroll
    for (int i = 0; i < HG; i++){
      accx[i] += w[i]*v.x;
      accy[i] += w[i]*v.y;
    }
  }
  float2* aggr = (float2*)(agg + (size_t)n*(HG*128));
  #pragma unroll
  for (int i = 0; i < HG; i++){
    float2 o; o.x = accx[i]; o.y = accy[i];
    aggr[i*64 + lane] = o;
  }
}

// ------- layer-2 output GEMM: out[n,c] = agg[n,:] . Wt[:,c] (+b2) -------
// block: 256 threads = 4 waves, each wave 16 nodes; lane = output column
// mode 0: out = acc + b2 ; mode 1: out = acc ; mode 2: out += acc + b2
template<int G>
__global__ void k_gemm_out(const float* __restrict__ agg, const float* __restrict__ Wt,
                           const float* __restrict__ b2, float* __restrict__ outp,
                           int mode){
  __shared__ float wl[64*65];
  int tid = threadIdx.x;
  int lane = tid & 63, wv = tid >> 6;
  int n0 = (blockIdx.x*4 + wv)*16;
  constexpr int K = G*128;
  float acc[16];
  #pragma unroll
  for (int i = 0; i < 16; i++) acc[i] = 0.f;
  for (int kt = 0; kt < K/64; kt++){
    __syncthreads();
    for (int idx = tid; idx < 4096; idx += 256){
      wl[(idx >> 6)*65 + (idx & 63)] = Wt[kt*4096 + idx];
    }
    __syncthreads();
    for (int k4 = 0; k4 < 16; k4++){
      float4 a[16];
      #pragma unroll
      for (int i = 0; i < 16; i++)
        a[i] = *(const float4*)&agg[(size_t)(n0+i)*K + kt*64 + k4*4];
      #pragma unroll
      for (int kk = 0; kk < 4; kk++){
        float wvv = wl[(k4*4 + kk)*65 + lane];
        #pragma unroll
        for (int i = 0; i < 16; i++){
          float av = (kk == 0) ? a[i].x : (kk == 1) ? a[i].y : (kk == 2) ? a[i].z : a[i].w;
          acc[i] += av * wvv;
        }
      }
    }
  }
  #pragma unroll
  for (int i = 0; i < 16; i++){
    int n = n0 + i;
    if (n < N_NODES){
      if (mode == 0)      outp[n*64 + lane] = acc[i] + b2[lane];
      else if (mode == 1) outp[n*64 + lane] = acc[i];
      else                outp[n*64 + lane] += acc[i] + b2[lane];
    }
  }
}

extern "C" void kernel_launch(void* const* d_in, const int* in_sizes, int n_in,
                              void* d_out, int out_size, void* d_ws, size_t ws_size,
                              hipStream_t stream){
  const float* x   = (const float*)d_in[0];
  const int*   ei  = (const int*)d_in[1];
  const float* W1  = (const float*)d_in[2];
  const float* as1 = (const float*)d_in[3];
  const float* ad1 = (const float*)d_in[4];
  const float* b1  = (const float*)d_in[5];
  const float* W2  = (const float*)d_in[6];
  const float* as2 = (const float*)d_in[7];
  const float* ad2 = (const float*)d_in[8];
  const float* b2  = (const float*)d_in[9];
  float* outp = (float*)d_out;

  auto A = [](size_t x_)->size_t{ return (x_ + 255) & ~(size_t)255; };
  const size_t SZ_AGG8 = (size_t)NPAD*1024*4;
  const size_t SZ_AGG4 = (size_t)NPAD*512*4;
  const size_t SZ_HR   = (size_t)N_NODES*128*4;
  const size_t SZ_ALS  = (size_t)N_NODES*8*4;
  const size_t SZ_EW   = (size_t)ET*8*4;
  const size_t SZ_RP   = (size_t)(N_NODES+1)*4;
  const size_t SZ_I    = (size_t)N_NODES*4;
  const size_t SZ_COL  = (size_t)ET*4;
  const size_t SZ_WT   = (size_t)65536*4;
  size_t fixed = A(SZ_HR) + 4*A(SZ_ALS) + A(SZ_EW) + A(SZ_RP) + 2*A(SZ_I)
               + A(SZ_COL) + 256 + 2*A(1024*4) + A(SZ_WT);
  bool single = (ws_size >= A(SZ_AGG8) + fixed);
  size_t sz_agg = single ? SZ_AGG8 : SZ_AGG4;

  char* p = (char*)d_ws;
  auto alloc = [&](size_t bytes) -> void* {
    void* r = (void*)p;
    p += (bytes + 255) & ~(size_t)255;
    return r;
  };
  float* agg = (float*)alloc(sz_agg);
  float* h1  = agg;                      // alias: h1 dead before agg is born
  float* hr  = (float*)alloc(SZ_HR);
  float* als1 = (float*)alloc(SZ_ALS);
  float* ald1 = (float*)alloc(SZ_ALS);
  float* als2 = (float*)alloc(SZ_ALS);
  float* ald2 = (float*)alloc(SZ_ALS);
  float* ew  = (float*)alloc(SZ_EW);
  int* row_ptr = (int*)alloc(SZ_RP);
  int* deg  = (int*)alloc(SZ_I);
  int* cnt  = (int*)alloc(SZ_I);
  int* col  = (int*)alloc(SZ_COL);
  int* flag = (int*)alloc(256);
  float* ws2 = (float*)alloc(1024*4);
  float* wd2 = (float*)alloc(1024*4);
  float* Wt  = (float*)alloc(SZ_WT);

  dim3 b256(256);
  // edge-index layout probe + CSR build
  k_detect<<<1, 64, 0, stream>>>(ei, flag);
  k_zero2<<<(N_NODES+255)/256, b256, 0, stream>>>(deg, cnt, N_NODES);
  k_degree<<<(ET+255)/256, b256, 0, stream>>>(ei, deg, flag);
  k_scan<<<1, 1024, 0, stream>>>(deg, row_ptr);
  k_fill<<<(ET+255)/256, b256, 0, stream>>>(ei, row_ptr, cnt, col, flag);
  // weight prep for layer 2
  k_wtilde<<<4, b256, 0, stream>>>(W2, as2, ad2, ws2, wd2);
  k_w2t<<<256, b256, 0, stream>>>(W2, Wt);

  int nwave_blocks = (N_NODES*64 + 255)/256;   // one wave per node
  // layer 1
  k_gemm_alpha1<<<(N_NODES+7)/8, 128, 0, stream>>>(x, W1, as1, ad1, h1, als1, ald1);
  k_attn<<<nwave_blocks, b256, 0, stream>>>(als1, ald1, row_ptr, col, ew);
  k_agg1<<<nwave_blocks, b256, 0, stream>>>(h1, ew, row_ptr, col, b1, hr,
                                            ws2, wd2, als2, ald2);
  // layer 2
  k_attn<<<nwave_blocks, b256, 0, stream>>>(als2, ald2, row_ptr, col, ew);
  int gout_blocks = (NPAD/64);                 // 782
  if (single){
    k_agg2n<8><<<nwave_blocks, b256, 0, stream>>>(hr, ew, row_ptr, col, agg, 0);
    k_gemm_out<8><<<gout_blocks, b256, 0, stream>>>(agg, Wt, b2, outp, 0);
  } else {
    k_agg2n<4><<<nwave_blocks, b256, 0, stream>>>(hr, ew, row_ptr, col, agg, 0);
    k_gemm_out<4><<<gout_blocks, b256, 0, stream>>>(agg, Wt, b2, outp, 1);
    k_agg2n<4><<<nwave_blocks, b256, 0, stream>>>(hr, ew, row_ptr, col, agg, 4);
    k_gemm_out<4><<<gout_blocks, b256, 0, stream>>>(agg, Wt + 512*64, b2, outp, 2);
  }
}

// Round 3
// 654.016 us; speedup vs baseline: 2.0931x; 2.0931x over previous
//
#include <hip/hip_runtime.h>

#define N_NODES 50000
#define N_EDGES 800000
#define ET (N_EDGES + N_NODES)   // 850000 incl. self loops
#define HEADS 8
#define NPAD 50048               // 782 blocks * 64 nodes
#define SCAN_NB 196              // ceil(50000/256)

typedef __attribute__((ext_vector_type(8))) short short8;
typedef __attribute__((ext_vector_type(4))) float f32x4;

__device__ __forceinline__ unsigned short f2bf(float f){
  union { float f; unsigned int u; } v; v.f = f;
  unsigned int u = v.u + 0x7fff + ((v.u >> 16) & 1);   // RNE
  return (unsigned short)(u >> 16);
}

// ---------- edge-index layout detection (int32 vs int64 storage) ----------
__global__ void k_detect(const int* __restrict__ ei, int* __restrict__ flag){
  if (blockIdx.x == 0 && threadIdx.x == 0){
    int zeros = 0;
    for (int i = 0; i < 64; i++){
      if (ei[2*i + 1] == 0) zeros++;
    }
    *flag = (zeros >= 60) ? 1 : 0;   // 1 => int64 little-endian layout
  }
}

__device__ __forceinline__ int edge_src(const int* ei, int e, int is64){
  if (e >= N_EDGES) return e - N_EDGES;          // self loop
  return is64 ? ei[2*e] : ei[e];
}
__device__ __forceinline__ int edge_dst(const int* ei, int e, int is64){
  if (e >= N_EDGES) return e - N_EDGES;          // self loop
  return is64 ? ei[2*(N_EDGES + e)] : ei[N_EDGES + e];
}

// ---------------- CSR build ----------------
__global__ void k_zero2(int* __restrict__ a, int* __restrict__ b, int n){
  int i = blockIdx.x*blockDim.x + threadIdx.x;
  if (i < n){ a[i] = 0; b[i] = 0; }
}

__global__ void k_degree(const int* __restrict__ ei, int* __restrict__ deg,
                         const int* __restrict__ flag){
  int e = blockIdx.x*blockDim.x + threadIdx.x;
  if (e >= ET) return;
  int is64 = *flag;
  int d = edge_dst(ei, e, is64);
  atomicAdd(&deg[d], 1);
}

// ---- 3-stage scan: per-block exclusive + block totals ----
__global__ void k_scan_part(const int* __restrict__ deg, int* __restrict__ loc,
                            int* __restrict__ part){
  __shared__ int lds[256];
  int t = threadIdx.x, i = blockIdx.x*256 + t;
  int v = (i < N_NODES) ? deg[i] : 0;
  lds[t] = v;
  __syncthreads();
  for (int off = 1; off < 256; off <<= 1){
    int x = (t >= off) ? lds[t - off] : 0;
    __syncthreads();
    lds[t] += x;
    __syncthreads();
  }
  if (i < N_NODES) loc[i] = lds[t] - v;          // local exclusive
  if (t == 255) part[blockIdx.x] = lds[255];
}

__global__ void k_scan_carry(int* __restrict__ part, int* __restrict__ carry){
  __shared__ int lds[256];
  int t = threadIdx.x;
  int v = (t < SCAN_NB) ? part[t] : 0;
  lds[t] = v;
  __syncthreads();
  for (int off = 1; off < 256; off <<= 1){
    int x = (t >= off) ? lds[t - off] : 0;
    __syncthreads();
    lds[t] += x;
    __syncthreads();
  }
  if (t < SCAN_NB) carry[t] = lds[t] - v;        // exclusive over blocks
}

__global__ void k_scan_add(const int* __restrict__ loc, const int* __restrict__ carry,
                           int* __restrict__ row_ptr){
  int i = blockIdx.x*blockDim.x + threadIdx.x;
  if (i < N_NODES) row_ptr[i] = loc[i] + carry[i >> 8];
  if (i == 0) row_ptr[N_NODES] = ET;
}

__global__ void k_fill(const int* __restrict__ ei, const int* __restrict__ row_ptr,
                       int* __restrict__ cnt, int* __restrict__ col,
                       const int* __restrict__ flag){
  int e = blockIdx.x*blockDim.x + threadIdx.x;
  if (e >= ET) return;
  int is64 = *flag;
  int s = edge_src(ei, e, is64);
  int d = edge_dst(ei, e, is64);
  int pos = atomicAdd(&cnt[d], 1);
  col[row_ptr[d] + pos] = s;
}

// ---------------- weight prep for layer 2 ----------------
// wtilde[k,h] = sum_d W2[k, h*64+d] * att[h,d]   (fold W2 into attention vecs)
__global__ void k_wtilde(const float* __restrict__ W2, const float* __restrict__ as2,
                         const float* __restrict__ ad2,
                         float* __restrict__ ws2, float* __restrict__ wd2){
  int t = blockIdx.x*blockDim.x + threadIdx.x;
  if (t >= 1024) return;
  int k = t >> 3, h = t & 7;
  float s = 0.f, d = 0.f;
  for (int dd = 0; dd < 64; dd++){
    float w = W2[k*512 + h*64 + dd];
    s += w * as2[h*64 + dd];
    d += w * ad2[h*64 + dd];
  }
  ws2[k*8 + h] = s;
  wd2[k*8 + h] = d;
}

// Bpack: B fragments for mfma_f32_16x16x32_bf16, 0.125 (head mean) folded in.
// t = ((kt*4 + nt)*64 + lane)*8 + j ;  k = kt*32 + (lane>>4)*8 + j ; c = nt*16 + (lane&15)
__global__ void k_w2pack(const float* __restrict__ W2, unsigned short* __restrict__ Bp){
  int t = blockIdx.x*blockDim.x + threadIdx.x;
  if (t >= 65536) return;
  int j = t & 7, lane = (t >> 3) & 63, nt = (t >> 9) & 3, kt = t >> 11;
  int k = kt*32 + (lane >> 4)*8 + j;
  int c = nt*16 + (lane & 15);
  int h = k >> 7, kk = k & 127;
  Bp[t] = f2bf(0.125f * W2[kk*512 + h*64 + c]);
}

// ---------------- layer 1: GEMM [N,128]x[128,128] + alpha_src/dst ----------------
__global__ void k_gemm_alpha1(const float* __restrict__ x, const float* __restrict__ W,
                              const float* __restrict__ asv, const float* __restrict__ adv,
                              float* __restrict__ h, float* __restrict__ als,
                              float* __restrict__ ald){
  __shared__ float xs[8][128];
  int c = threadIdx.x;           // 0..127 (output column)
  int n0 = blockIdx.x * 8;
  #pragma unroll
  for (int i = 0; i < 8; i++){
    int n = n0 + i;
    xs[i][c] = (n < N_NODES) ? x[n*128 + c] : 0.f;
  }
  __syncthreads();
  float acc[8] = {0.f,0.f,0.f,0.f,0.f,0.f,0.f,0.f};
  for (int k = 0; k < 128; k++){
    float w = W[k*128 + c];
    #pragma unroll
    for (int i = 0; i < 8; i++) acc[i] += xs[i][k] * w;
  }
  float a_s = asv[c], a_d = adv[c];   // flat [8,16] -> index c
  #pragma unroll
  for (int i = 0; i < 8; i++){
    int n = n0 + i;
    if (n >= N_NODES) break;          // block-uniform
    h[n*128 + c] = acc[i];
    float vs = acc[i] * a_s;
    float vd = acc[i] * a_d;
    #pragma unroll
    for (int off = 1; off < 16; off <<= 1){
      vs += __shfl_xor(vs, off, 64);
      vd += __shfl_xor(vd, off, 64);
    }
    if ((c & 15) == 0){
      als[n*8 + (c >> 4)] = vs;
      ald[n*8 + (c >> 4)] = vd;
    }
  }
}

// ---------------- edge softmax weights (one wave per dst node) ----------------
__global__ void k_attn(const float* __restrict__ als, const float* __restrict__ ald,
                       const int* __restrict__ row_ptr, const int* __restrict__ col,
                       float* __restrict__ ew){
  int gid = blockIdx.x*blockDim.x + threadIdx.x;
  int n = gid >> 6;
  int lane = threadIdx.x & 63;
  if (n >= N_NODES) return;
  int beg = row_ptr[n], end = row_ptr[n+1];
  int items = (end - beg) * 8;        // (edge, head) pairs
  int h = lane & 7;                   // fixed head class per lane
  float ad = ald[n*8 + h];
  float m = -1e30f;
  for (int it = lane; it < items; it += 64){
    int s = col[beg + (it >> 3)];
    float a = als[s*8 + h] + ad;
    float e = (a > 0.f) ? a : 0.2f*a;
    m = fmaxf(m, e);
  }
  m = fmaxf(m, __shfl_xor(m, 8, 64));
  m = fmaxf(m, __shfl_xor(m, 16, 64));
  m = fmaxf(m, __shfl_xor(m, 32, 64));
  float den = 0.f;
  for (int it = lane; it < items; it += 64){
    int s = col[beg + (it >> 3)];
    float a = als[s*8 + h] + ad;
    float e = (a > 0.f) ? a : 0.2f*a;
    den += __expf(e - m);
  }
  den += __shfl_xor(den, 8, 64);
  den += __shfl_xor(den, 16, 64);
  den += __shfl_xor(den, 32, 64);
  float inv = 1.f / (den + 1e-16f);
  for (int it = lane; it < items; it += 64){
    int j = beg + (it >> 3);
    int s = col[j];
    float a = als[s*8 + h] + ad;
    float e = (a > 0.f) ? a : 0.2f*a;
    ew[(size_t)j*8 + h] = __expf(e - m) * inv;
  }
}

// ------- layer-1 aggregation: concat heads, +b1, relu, + layer-2 logits -------
__global__ void k_agg1(const float* __restrict__ h, const float* __restrict__ ew,
                       const int* __restrict__ row_ptr, const int* __restrict__ col,
                       const float* __restrict__ bias, float* __restrict__ outp,
                       const float* __restrict__ ws2, const float* __restrict__ wd2,
                       float* __restrict__ als2, float* __restrict__ ald2){
  int gid = blockIdx.x*blockDim.x + threadIdx.x;
  int n = gid >> 6;
  int lane = threadIdx.x & 63;
  if (n >= N_NODES) return;
  int beg = row_ptr[n], end = row_ptr[n+1];
  int c0 = lane, c1 = lane + 64;
  int h0 = c0 >> 4, h1c = c1 >> 4;
  float acc0 = 0.f, acc1 = 0.f;
  for (int j = beg; j < end; j++){
    int s = col[j];
    float w0 = ew[(size_t)j*8 + h0];
    float w1 = ew[(size_t)j*8 + h1c];
    acc0 += w0 * h[s*128 + c0];
    acc1 += w1 * h[s*128 + c1];
  }
  float o0 = acc0 + bias[c0];
  float o1 = acc1 + bias[c1];
  o0 = o0 > 0.f ? o0 : 0.f;
  o1 = o1 > 0.f ? o1 : 0.f;
  outp[n*128 + c0] = o0;
  outp[n*128 + c1] = o1;
  // epilogue: layer-2 attention logits als2/ald2 = hr . wtilde
  #pragma unroll
  for (int hh = 0; hh < 8; hh++){
    float vs = o0*ws2[c0*8 + hh] + o1*ws2[c1*8 + hh];
    float vd = o0*wd2[c0*8 + hh] + o1*wd2[c1*8 + hh];
    #pragma unroll
    for (int off = 1; off < 64; off <<= 1){
      vs += __shfl_xor(vs, off, 64);
      vd += __shfl_xor(vd, off, 64);
    }
    if (lane == 0){
      als2[n*8 + hh] = vs;
      ald2[n*8 + hh] = vd;
    }
  }
}

// ------- layer-2 gather: per-head weighted sums of hr -> bf16 agg[N,1024] -------
__global__ void k_agg2n(const float* __restrict__ hr, const float* __restrict__ ew,
                        const int* __restrict__ row_ptr, const int* __restrict__ col,
                        unsigned int* __restrict__ aggb){
  int gid = blockIdx.x*blockDim.x + threadIdx.x;
  int n = gid >> 6;
  int lane = threadIdx.x & 63;
  if (n >= N_NODES) return;
  int beg = row_ptr[n], end = row_ptr[n+1];
  const float2* hr2 = (const float2*)hr;
  float accx[8], accy[8];
  #pragma unroll
  for (int i = 0; i < 8; i++){ accx[i] = 0.f; accy[i] = 0.f; }
  for (int j = beg; j < end; j++){
    int s = col[j];
    float2 v = hr2[(size_t)s*64 + lane];
    const float* wp = ew + (size_t)j*8;
    float4 wa = *(const float4*)wp;
    float4 wb = *(const float4*)(wp + 4);
    float w[8] = {wa.x, wa.y, wa.z, wa.w, wb.x, wb.y, wb.z, wb.w};
    #pragma unroll
    for (int i = 0; i < 8; i++){
      accx[i] += w[i]*v.x;
      accy[i] += w[i]*v.y;
    }
  }
  // agg[n][h*128 + 2*lane .. +1] as packed bf16 pair
  unsigned int* ar = aggb + (size_t)n*512 + lane;
  #pragma unroll
  for (int i = 0; i < 8; i++){
    unsigned int pk = (unsigned int)f2bf(accx[i]) | ((unsigned int)f2bf(accy[i]) << 16);
    ar[i*64] = pk;
  }
}

// ------- layer-2 output GEMM via MFMA: out = agg[N,1024] @ Wt[1024,64] + b2 -------
// block = 4 waves; wave -> 16 nodes x 64 cols; K = 1024 (8 heads x 128)
__global__ void __launch_bounds__(256) k_gemm_out_mfma(
    const unsigned short* __restrict__ aggb, const unsigned short* __restrict__ Bp,
    const float* __restrict__ b2, float* __restrict__ outp){
  int tid = threadIdx.x;
  int lane = tid & 63, wv = tid >> 6;
  int n0 = blockIdx.x*64 + wv*16;
  int rowA = n0 + (lane & 15);
  const unsigned short* arow = aggb + (size_t)rowA*1024 + (lane >> 4)*8;
  f32x4 acc[4];
  #pragma unroll
  for (int i = 0; i < 4; i++) acc[i] = (f32x4){0.f,0.f,0.f,0.f};
  for (int kt = 0; kt < 32; kt++){
    short8 af = *(const short8*)(arow + kt*32);
    #pragma unroll
    for (int nt = 0; nt < 4; nt++){
      short8 bf = *(const short8*)(Bp + (((kt*4 + nt)*64 + lane) << 3));
      acc[nt] = __builtin_amdgcn_mfma_f32_16x16x32_bf16(af, bf, acc[nt], 0, 0, 0);
    }
  }
  int r0 = n0 + (lane >> 4)*4;     // C/D: col=lane&15, row=(lane>>4)*4+reg  [m89]
  #pragma unroll
  for (int nt = 0; nt < 4; nt++){
    int c = nt*16 + (lane & 15);
    float bb = b2[c];
    #pragma unroll
    for (int r = 0; r < 4; r++){
      int n = r0 + r;
      if (n < N_NODES) outp[n*64 + c] = acc[nt][r] + bb;
    }
  }
}

extern "C" void kernel_launch(void* const* d_in, const int* in_sizes, int n_in,
                              void* d_out, int out_size, void* d_ws, size_t ws_size,
                              hipStream_t stream){
  const float* x   = (const float*)d_in[0];
  const int*   ei  = (const int*)d_in[1];
  const float* W1  = (const float*)d_in[2];
  const float* as1 = (const float*)d_in[3];
  const float* ad1 = (const float*)d_in[4];
  const float* b1  = (const float*)d_in[5];
  const float* W2  = (const float*)d_in[6];
  const float* as2 = (const float*)d_in[7];
  const float* ad2 = (const float*)d_in[8];
  const float* b2  = (const float*)d_in[9];
  float* outp = (float*)d_out;

  char* p = (char*)d_ws;
  auto alloc = [&](size_t bytes) -> void* {
    void* r = (void*)p;
    p += (bytes + 255) & ~(size_t)255;
    return r;
  };
  unsigned int* aggb = (unsigned int*)alloc((size_t)NPAD*1024*2);  // bf16 [NPAD,1024]
  float* h1  = (float*)aggb;             // alias: h1 dead before aggb is born
  float* hr  = (float*)alloc((size_t)N_NODES*128*4);
  float* als1 = (float*)alloc((size_t)N_NODES*8*4);
  float* ald1 = (float*)alloc((size_t)N_NODES*8*4);
  float* als2 = (float*)alloc((size_t)N_NODES*8*4);
  float* ald2 = (float*)alloc((size_t)N_NODES*8*4);
  float* ew  = (float*)alloc((size_t)ET*8*4);
  int* row_ptr = (int*)alloc((size_t)(N_NODES+1)*4);
  int* deg  = (int*)alloc((size_t)N_NODES*4);
  int* cnt  = (int*)alloc((size_t)N_NODES*4);
  int* col  = (int*)alloc((size_t)ET*4);
  int* loc  = (int*)alloc((size_t)N_NODES*4);
  int* part = (int*)alloc(256*4);
  int* carry= (int*)alloc(256*4);
  int* flag = (int*)alloc(256);
  float* ws2 = (float*)alloc(1024*4);
  float* wd2 = (float*)alloc(1024*4);
  unsigned short* Bp = (unsigned short*)alloc((size_t)65536*2);

  dim3 b256(256);
  // edge-index layout probe + CSR build
  k_detect<<<1, 64, 0, stream>>>(ei, flag);
  k_zero2<<<(N_NODES+255)/256, b256, 0, stream>>>(deg, cnt, N_NODES);
  k_degree<<<(ET+255)/256, b256, 0, stream>>>(ei, deg, flag);
  k_scan_part<<<SCAN_NB, b256, 0, stream>>>(deg, loc, part);
  k_scan_carry<<<1, b256, 0, stream>>>(part, carry);
  k_scan_add<<<SCAN_NB, b256, 0, stream>>>(loc, carry, row_ptr);
  k_fill<<<(ET+255)/256, b256, 0, stream>>>(ei, row_ptr, cnt, col, flag);
  // weight prep for layer 2
  k_wtilde<<<4, b256, 0, stream>>>(W2, as2, ad2, ws2, wd2);
  k_w2pack<<<256, b256, 0, stream>>>(W2, Bp);

  int nwave_blocks = (N_NODES*64 + 255)/256;   // one wave per node
  // layer 1
  k_gemm_alpha1<<<(N_NODES+7)/8, 128, 0, stream>>>(x, W1, as1, ad1, h1, als1, ald1);
  k_attn<<<nwave_blocks, b256, 0, stream>>>(als1, ald1, row_ptr, col, ew);
  k_agg1<<<nwave_blocks, b256, 0, stream>>>(h1, ew, row_ptr, col, b1, hr,
                                            ws2, wd2, als2, ald2);
  // layer 2
  k_attn<<<nwave_blocks, b256, 0, stream>>>(als2, ald2, row_ptr, col, ew);
  k_agg2n<<<nwave_blocks, b256, 0, stream>>>(hr, ew, row_ptr, col, aggb);
  k_gemm_out_mfma<<<NPAD/64, b256, 0, stream>>>((const unsigned short*)aggb, Bp, b2, outp);
}

// Round 4
// 507.123 us; speedup vs baseline: 2.6994x; 1.2897x over previous
//
#include <hip/hip_runtime.h>

#define N_NODES 50000
#define N_EDGES 800000
#define ET (N_EDGES + N_NODES)   // 850000 incl. self loops
#define HEADS 8
#define NPAD 50048               // 782 blocks * 64 nodes
#define SCAN_NB 196              // ceil(50000/256)

typedef __attribute__((ext_vector_type(8))) short short8;
typedef __attribute__((ext_vector_type(4))) float f32x4;

__device__ __forceinline__ unsigned short f2bf(float f){
  union { float f; unsigned int u; } v; v.f = f;
  unsigned int u = v.u + 0x7fff + ((v.u >> 16) & 1);   // RNE
  return (unsigned short)(u >> 16);
}

// ---------- edge-index layout detection (int32 vs int64 storage) ----------
__global__ void k_detect(const int* __restrict__ ei, int* __restrict__ flag){
  if (blockIdx.x == 0 && threadIdx.x == 0){
    int zeros = 0;
    for (int i = 0; i < 64; i++){
      if (ei[2*i + 1] == 0) zeros++;
    }
    *flag = (zeros >= 60) ? 1 : 0;   // 1 => int64 little-endian layout
  }
}

__device__ __forceinline__ int edge_src(const int* ei, int e, int is64){
  if (e >= N_EDGES) return e - N_EDGES;          // self loop
  return is64 ? ei[2*e] : ei[e];
}
__device__ __forceinline__ int edge_dst(const int* ei, int e, int is64){
  if (e >= N_EDGES) return e - N_EDGES;          // self loop
  return is64 ? ei[2*(N_EDGES + e)] : ei[N_EDGES + e];
}

// ---------------- CSR build ----------------
__global__ void k_zero2(int* __restrict__ a, int* __restrict__ b, int n){
  int i = blockIdx.x*blockDim.x + threadIdx.x;
  if (i < n){ a[i] = 0; b[i] = 0; }
}

__global__ void k_degree(const int* __restrict__ ei, int* __restrict__ deg,
                         const int* __restrict__ flag){
  int e = blockIdx.x*blockDim.x + threadIdx.x;
  if (e >= ET) return;
  int is64 = *flag;
  int d = edge_dst(ei, e, is64);
  atomicAdd(&deg[d], 1);
}

// ---- 3-stage scan ----
__global__ void k_scan_part(const int* __restrict__ deg, int* __restrict__ loc,
                            int* __restrict__ part){
  __shared__ int lds[256];
  int t = threadIdx.x, i = blockIdx.x*256 + t;
  int v = (i < N_NODES) ? deg[i] : 0;
  lds[t] = v;
  __syncthreads();
  for (int off = 1; off < 256; off <<= 1){
    int x = (t >= off) ? lds[t - off] : 0;
    __syncthreads();
    lds[t] += x;
    __syncthreads();
  }
  if (i < N_NODES) loc[i] = lds[t] - v;          // local exclusive
  if (t == 255) part[blockIdx.x] = lds[255];
}

__global__ void k_scan_carry(int* __restrict__ part, int* __restrict__ carry){
  __shared__ int lds[256];
  int t = threadIdx.x;
  int v = (t < SCAN_NB) ? part[t] : 0;
  lds[t] = v;
  __syncthreads();
  for (int off = 1; off < 256; off <<= 1){
    int x = (t >= off) ? lds[t - off] : 0;
    __syncthreads();
    lds[t] += x;
    __syncthreads();
  }
  if (t < SCAN_NB) carry[t] = lds[t] - v;        // exclusive over blocks
}

__global__ void k_scan_add(const int* __restrict__ loc, const int* __restrict__ carry,
                           int* __restrict__ row_ptr){
  int i = blockIdx.x*blockDim.x + threadIdx.x;
  if (i < N_NODES) row_ptr[i] = loc[i] + carry[i >> 8];
  if (i == 0) row_ptr[N_NODES] = ET;
}

__global__ void k_fill(const int* __restrict__ ei, const int* __restrict__ row_ptr,
                       int* __restrict__ cnt, int* __restrict__ col,
                       const int* __restrict__ flag){
  int e = blockIdx.x*blockDim.x + threadIdx.x;
  if (e >= ET) return;
  int is64 = *flag;
  int s = edge_src(ei, e, is64);
  int d = edge_dst(ei, e, is64);
  int pos = atomicAdd(&cnt[d], 1);
  col[row_ptr[d] + pos] = s;
}

// ---------------- weight prep for layer 2 ----------------
// wtilde[h*128+k] = sum_d W2[k, h*64+d] * att[h,d]   (transposed layout)
__global__ void k_wtilde(const float* __restrict__ W2, const float* __restrict__ as2,
                         const float* __restrict__ ad2,
                         float* __restrict__ ws2, float* __restrict__ wd2){
  int t = blockIdx.x*blockDim.x + threadIdx.x;
  if (t >= 1024) return;
  int k = t >> 3, h = t & 7;
  float s = 0.f, d = 0.f;
  for (int dd = 0; dd < 64; dd++){
    float w = W2[k*512 + h*64 + dd];
    s += w * as2[h*64 + dd];
    d += w * ad2[h*64 + dd];
  }
  ws2[h*128 + k] = s;
  wd2[h*128 + k] = d;
}

// Bpack: B fragments for mfma_f32_16x16x32_bf16, 0.125 (head mean) folded in.
__global__ void k_w2pack(const float* __restrict__ W2, unsigned short* __restrict__ Bp){
  int t = blockIdx.x*blockDim.x + threadIdx.x;
  if (t >= 65536) return;
  int j = t & 7, lane = (t >> 3) & 63, nt = (t >> 9) & 3, kt = t >> 11;
  int k = kt*32 + (lane >> 4)*8 + j;
  int c = nt*16 + (lane & 15);
  int h = k >> 7, kk = k & 127;
  Bp[t] = f2bf(0.125f * W2[kk*512 + h*64 + c]);
}

// ---------------- layer 1: GEMM [N,128]x[128,128] + alpha_src/dst ----------------
__global__ void k_gemm_alpha1(const float* __restrict__ x, const float* __restrict__ W,
                              const float* __restrict__ asv, const float* __restrict__ adv,
                              float* __restrict__ h, float* __restrict__ als,
                              float* __restrict__ ald){
  __shared__ float xs[8][128];
  int c = threadIdx.x;           // 0..127 (output column)
  int n0 = blockIdx.x * 8;
  #pragma unroll
  for (int i = 0; i < 8; i++){
    int n = n0 + i;
    xs[i][c] = (n < N_NODES) ? x[n*128 + c] : 0.f;
  }
  __syncthreads();
  float acc[8] = {0.f,0.f,0.f,0.f,0.f,0.f,0.f,0.f};
  for (int k = 0; k < 128; k++){
    float w = W[k*128 + c];
    #pragma unroll
    for (int i = 0; i < 8; i++) acc[i] += xs[i][k] * w;
  }
  float a_s = asv[c], a_d = adv[c];   // flat [8,16] -> index c
  #pragma unroll
  for (int i = 0; i < 8; i++){
    int n = n0 + i;
    if (n >= N_NODES) break;          // block-uniform
    h[n*128 + c] = acc[i];
    float vs = acc[i] * a_s;
    float vd = acc[i] * a_d;
    #pragma unroll
    for (int off = 1; off < 16; off <<= 1){
      vs += __shfl_xor(vs, off, 64);
      vd += __shfl_xor(vd, off, 64);
    }
    if ((c & 15) == 0){
      als[n*8 + (c >> 4)] = vs;
      ald[n*8 + (c >> 4)] = vd;
    }
  }
}

// ------ edge softmax: 1 random-gather pass (online m,l) + 1 coalesced pass ------
__global__ void k_attn(const float* __restrict__ als, const float* __restrict__ ald,
                       const int* __restrict__ row_ptr, const int* __restrict__ col,
                       float* __restrict__ ew){
  int gid = blockIdx.x*blockDim.x + threadIdx.x;
  int n = gid >> 6;
  int lane = threadIdx.x & 63;
  if (n >= N_NODES) return;
  int beg = row_ptr[n], end = row_ptr[n+1];
  int items = (end - beg) * 8;        // (edge, head) pairs
  int h = lane & 7;                   // fixed head class per lane
  float ad = ald[n*8 + h];
  float* ewb = ew + (size_t)beg*8;
  float m = -1e30f, l = 0.f;
  int it = lane;
  for (; it + 64 < items; it += 128){
    int s0 = col[beg + (it >> 3)];
    int s1 = col[beg + ((it + 64) >> 3)];
    float a0 = als[s0*8 + h] + ad; a0 = (a0 > 0.f) ? a0 : 0.2f*a0;
    float a1 = als[s1*8 + h] + ad; a1 = (a1 > 0.f) ? a1 : 0.2f*a1;
    ewb[it] = a0;
    ewb[it + 64] = a1;
    float nm = fmaxf(m, fmaxf(a0, a1));
    l = l*__expf(m - nm) + __expf(a0 - nm) + __expf(a1 - nm);
    m = nm;
  }
  for (; it < items; it += 64){
    int s = col[beg + (it >> 3)];
    float a = als[s*8 + h] + ad; a = (a > 0.f) ? a : 0.2f*a;
    ewb[it] = a;
    float nm = fmaxf(m, a);
    l = l*__expf(m - nm) + __expf(a - nm);
    m = nm;
  }
  // combine (m,l) across lanes of same head (stride 8)
  #pragma unroll
  for (int off = 8; off < 64; off <<= 1){
    float mo = __shfl_xor(m, off, 64);
    float lo = __shfl_xor(l, off, 64);
    float nm = fmaxf(m, mo);
    l = l*__expf(m - nm) + lo*__expf(mo - nm);
    m = nm;
  }
  float inv = 1.f / (l + 1e-16f);
  // pass 2: coalesced in-place normalize (each lane re-reads its own stores)
  for (int it2 = lane; it2 < items; it2 += 64){
    float e = ewb[it2];
    ewb[it2] = __expf(e - m) * inv;
  }
}

// ------- layer-1 aggregation: concat heads, +b1, relu, + layer-2 logits -------
// lane owns channels {2*lane, 2*lane+1}; head = lane>>3; unroll 8 for MLP
__global__ void k_agg1(const float* __restrict__ h, const float* __restrict__ ew,
                       const int* __restrict__ row_ptr, const int* __restrict__ col,
                       const float* __restrict__ bias, float* __restrict__ outp,
                       const float* __restrict__ ws2, const float* __restrict__ wd2,
                       float* __restrict__ als2, float* __restrict__ ald2){
  int gid = blockIdx.x*blockDim.x + threadIdx.x;
  int n = gid >> 6;
  int lane = threadIdx.x & 63;
  if (n >= N_NODES) return;
  int beg = row_ptr[n], end = row_ptr[n+1];
  int hh0 = lane >> 3;
  const float2* h2p = (const float2*)h;
  float ax = 0.f, ay = 0.f;
  int j = beg;
  for (; j + 7 < end; j += 8){
    int s[8]; float w[8]; float2 v[8];
    #pragma unroll
    for (int u = 0; u < 8; u++) s[u] = col[j + u];
    #pragma unroll
    for (int u = 0; u < 8; u++) w[u] = ew[(size_t)(j + u)*8 + hh0];
    #pragma unroll
    for (int u = 0; u < 8; u++) v[u] = h2p[(size_t)s[u]*64 + lane];
    #pragma unroll
    for (int u = 0; u < 8; u++){ ax += w[u]*v[u].x; ay += w[u]*v[u].y; }
  }
  for (; j < end; j++){
    int s = col[j];
    float w = ew[(size_t)j*8 + hh0];
    float2 v = h2p[(size_t)s*64 + lane];
    ax += w*v.x; ay += w*v.y;
  }
  float2 bb = ((const float2*)bias)[lane];
  float o0 = fmaxf(ax + bb.x, 0.f);
  float o1 = fmaxf(ay + bb.y, 0.f);
  float2 oo; oo.x = o0; oo.y = o1;
  ((float2*)outp)[(size_t)n*64 + lane] = oo;
  // epilogue: layer-2 attention logits (full 64-lane butterfly per head)
  const float2* wsp = (const float2*)ws2;
  const float2* wdp = (const float2*)wd2;
  #pragma unroll
  for (int hh = 0; hh < 8; hh++){
    float2 a = wsp[hh*64 + lane];
    float2 b = wdp[hh*64 + lane];
    float vs = o0*a.x + o1*a.y;
    float vd = o0*b.x + o1*b.y;
    #pragma unroll
    for (int off = 1; off < 64; off <<= 1){
      vs += __shfl_xor(vs, off, 64);
      vd += __shfl_xor(vd, off, 64);
    }
    if (lane == 0){
      als2[n*8 + hh] = vs;
      ald2[n*8 + hh] = vd;
    }
  }
}

// ------- layer-2 gather: per-head weighted sums of hr -> bf16 agg[N,1024] -------
__global__ void k_agg2n(const float* __restrict__ hr, const float* __restrict__ ew,
                        const int* __restrict__ row_ptr, const int* __restrict__ col,
                        unsigned int* __restrict__ aggb){
  int gid = blockIdx.x*blockDim.x + threadIdx.x;
  int n = gid >> 6;
  int lane = threadIdx.x & 63;
  if (n >= N_NODES) return;
  int beg = row_ptr[n], end = row_ptr[n+1];
  const float2* hr2 = (const float2*)hr;
  float accx[8], accy[8];
  #pragma unroll
  for (int i = 0; i < 8; i++){ accx[i] = 0.f; accy[i] = 0.f; }
  int j = beg;
  for (; j + 3 < end; j += 4){
    int s0 = col[j], s1 = col[j+1], s2 = col[j+2], s3 = col[j+3];
    float2 v0 = hr2[(size_t)s0*64 + lane];
    float2 v1 = hr2[(size_t)s1*64 + lane];
    float2 v2 = hr2[(size_t)s2*64 + lane];
    float2 v3 = hr2[(size_t)s3*64 + lane];
    float4 wa0 = *(const float4*)(ew + (size_t)j*8);
    float4 wb0 = *(const float4*)(ew + (size_t)j*8 + 4);
    float4 wa1 = *(const float4*)(ew + (size_t)(j+1)*8);
    float4 wb1 = *(const float4*)(ew + (size_t)(j+1)*8 + 4);
    float4 wa2 = *(const float4*)(ew + (size_t)(j+2)*8);
    float4 wb2 = *(const float4*)(ew + (size_t)(j+2)*8 + 4);
    float4 wa3 = *(const float4*)(ew + (size_t)(j+3)*8);
    float4 wb3 = *(const float4*)(ew + (size_t)(j+3)*8 + 4);
    float w0[8] = {wa0.x,wa0.y,wa0.z,wa0.w, wb0.x,wb0.y,wb0.z,wb0.w};
    float w1[8] = {wa1.x,wa1.y,wa1.z,wa1.w, wb1.x,wb1.y,wb1.z,wb1.w};
    float w2[8] = {wa2.x,wa2.y,wa2.z,wa2.w, wb2.x,wb2.y,wb2.z,wb2.w};
    float w3[8] = {wa3.x,wa3.y,wa3.z,wa3.w, wb3.x,wb3.y,wb3.z,wb3.w};
    #pragma unroll
    for (int i = 0; i < 8; i++){
      accx[i] += w0[i]*v0.x + w1[i]*v1.x + w2[i]*v2.x + w3[i]*v3.x;
      accy[i] += w0[i]*v0.y + w1[i]*v1.y + w2[i]*v2.y + w3[i]*v3.y;
    }
  }
  for (; j < end; j++){
    int s = col[j];
    float2 v = hr2[(size_t)s*64 + lane];
    float4 wa = *(const float4*)(ew + (size_t)j*8);
    float4 wb = *(const float4*)(ew + (size_t)j*8 + 4);
    float w[8] = {wa.x, wa.y, wa.z, wa.w, wb.x, wb.y, wb.z, wb.w};
    #pragma unroll
    for (int i = 0; i < 8; i++){
      accx[i] += w[i]*v.x;
      accy[i] += w[i]*v.y;
    }
  }
  unsigned int* ar = aggb + (size_t)n*512 + lane;
  #pragma unroll
  for (int i = 0; i < 8; i++){
    unsigned int pk = (unsigned int)f2bf(accx[i]) | ((unsigned int)f2bf(accy[i]) << 16);
    ar[i*64] = pk;
  }
}

// ------- layer-2 output GEMM via MFMA: out = agg[N,1024] @ Wt[1024,64] + b2 -------
__global__ void __launch_bounds__(256) k_gemm_out_mfma(
    const unsigned short* __restrict__ aggb, const unsigned short* __restrict__ Bp,
    const float* __restrict__ b2, float* __restrict__ outp){
  int tid = threadIdx.x;
  int lane = tid & 63, wv = tid >> 6;
  int n0 = blockIdx.x*64 + wv*16;
  int rowA = n0 + (lane & 15);
  const unsigned short* arow = aggb + (size_t)rowA*1024 + (lane >> 4)*8;
  f32x4 acc[4];
  #pragma unroll
  for (int i = 0; i < 4; i++) acc[i] = (f32x4){0.f,0.f,0.f,0.f};
  for (int kt = 0; kt < 32; kt++){
    short8 af = *(const short8*)(arow + kt*32);
    #pragma unroll
    for (int nt = 0; nt < 4; nt++){
      short8 bf = *(const short8*)(Bp + (((kt*4 + nt)*64 + lane) << 3));
      acc[nt] = __builtin_amdgcn_mfma_f32_16x16x32_bf16(af, bf, acc[nt], 0, 0, 0);
    }
  }
  int r0 = n0 + (lane >> 4)*4;     // C/D: col=lane&15, row=(lane>>4)*4+reg  [m89]
  #pragma unroll
  for (int nt = 0; nt < 4; nt++){
    int c = nt*16 + (lane & 15);
    float bb = b2[c];
    #pragma unroll
    for (int r = 0; r < 4; r++){
      int n = r0 + r;
      if (n < N_NODES) outp[n*64 + c] = acc[nt][r] + bb;
    }
  }
}

extern "C" void kernel_launch(void* const* d_in, const int* in_sizes, int n_in,
                              void* d_out, int out_size, void* d_ws, size_t ws_size,
                              hipStream_t stream){
  const float* x   = (const float*)d_in[0];
  const int*   ei  = (const int*)d_in[1];
  const float* W1  = (const float*)d_in[2];
  const float* as1 = (const float*)d_in[3];
  const float* ad1 = (const float*)d_in[4];
  const float* b1  = (const float*)d_in[5];
  const float* W2  = (const float*)d_in[6];
  const float* as2 = (const float*)d_in[7];
  const float* ad2 = (const float*)d_in[8];
  const float* b2  = (const float*)d_in[9];
  float* outp = (float*)d_out;

  char* p = (char*)d_ws;
  auto alloc = [&](size_t bytes) -> void* {
    void* r = (void*)p;
    p += (bytes + 255) & ~(size_t)255;
    return r;
  };
  unsigned int* aggb = (unsigned int*)alloc((size_t)NPAD*1024*2);  // bf16 [NPAD,1024]
  float* h1  = (float*)aggb;             // alias: h1 dead before aggb is born
  float* hr  = (float*)alloc((size_t)N_NODES*128*4);
  float* als1 = (float*)alloc((size_t)N_NODES*8*4);
  float* ald1 = (float*)alloc((size_t)N_NODES*8*4);
  float* als2 = (float*)alloc((size_t)N_NODES*8*4);
  float* ald2 = (float*)alloc((size_t)N_NODES*8*4);
  float* ew  = (float*)alloc((size_t)ET*8*4);
  int* row_ptr = (int*)alloc((size_t)(N_NODES+1)*4);
  int* deg  = (int*)alloc((size_t)N_NODES*4);
  int* cnt  = (int*)alloc((size_t)N_NODES*4);
  int* col  = (int*)alloc((size_t)ET*4);
  int* loc  = (int*)alloc((size_t)N_NODES*4);
  int* part = (int*)alloc(256*4);
  int* carry= (int*)alloc(256*4);
  int* flag = (int*)alloc(256);
  float* ws2 = (float*)alloc(1024*4);
  float* wd2 = (float*)alloc(1024*4);
  unsigned short* Bp = (unsigned short*)alloc((size_t)65536*2);

  dim3 b256(256);
  // edge-index layout probe + CSR build
  k_detect<<<1, 64, 0, stream>>>(ei, flag);
  k_zero2<<<(N_NODES+255)/256, b256, 0, stream>>>(deg, cnt, N_NODES);
  k_degree<<<(ET+255)/256, b256, 0, stream>>>(ei, deg, flag);
  k_scan_part<<<SCAN_NB, b256, 0, stream>>>(deg, loc, part);
  k_scan_carry<<<1, b256, 0, stream>>>(part, carry);
  k_scan_add<<<SCAN_NB, b256, 0, stream>>>(loc, carry, row_ptr);
  k_fill<<<(ET+255)/256, b256, 0, stream>>>(ei, row_ptr, cnt, col, flag);
  // weight prep for layer 2
  k_wtilde<<<4, b256, 0, stream>>>(W2, as2, ad2, ws2, wd2);
  k_w2pack<<<256, b256, 0, stream>>>(W2, Bp);

  int nwave_blocks = (N_NODES*64 + 255)/256;   // one wave per node
  // layer 1
  k_gemm_alpha1<<<(N_NODES+7)/8, 128, 0, stream>>>(x, W1, as1, ad1, h1, als1, ald1);
  k_attn<<<nwave_blocks, b256, 0, stream>>>(als1, ald1, row_ptr, col, ew);
  k_agg1<<<nwave_blocks, b256, 0, stream>>>(h1, ew, row_ptr, col, b1, hr,
                                            ws2, wd2, als2, ald2);
  // layer 2
  k_attn<<<nwave_blocks, b256, 0, stream>>>(als2, ald2, row_ptr, col, ew);
  k_agg2n<<<nwave_blocks, b256, 0, stream>>>(hr, ew, row_ptr, col, aggb);
  k_gemm_out_mfma<<<NPAD/64, b256, 0, stream>>>((const unsigned short*)aggb, Bp, b2, outp);
}

// Round 5
// 451.735 us; speedup vs baseline: 3.0304x; 1.1226x over previous
//
#include <hip/hip_runtime.h>

#define N_NODES 50000
#define N_EDGES 800000
#define ET (N_EDGES + N_NODES)   // 850000 incl. self loops
#define HEADS 8
#define NPAD 50048               // 782 blocks * 64 nodes
#define SCAN_NB 196              // ceil(50000/256)

typedef __attribute__((ext_vector_type(8))) _Float16 half8;
typedef __attribute__((ext_vector_type(2))) _Float16 half2v;
typedef __attribute__((ext_vector_type(4))) float f32x4;

// ---------- edge-index layout detection (int32 vs int64 storage) ----------
__global__ void k_detect(const int* __restrict__ ei, int* __restrict__ flag){
  if (blockIdx.x == 0 && threadIdx.x == 0){
    int zeros = 0;
    for (int i = 0; i < 64; i++){
      if (ei[2*i + 1] == 0) zeros++;
    }
    *flag = (zeros >= 60) ? 1 : 0;   // 1 => int64 little-endian layout
  }
}

__device__ __forceinline__ int edge_src(const int* ei, int e, int is64){
  if (e >= N_EDGES) return e - N_EDGES;          // self loop
  return is64 ? ei[2*e] : ei[e];
}
__device__ __forceinline__ int edge_dst(const int* ei, int e, int is64){
  if (e >= N_EDGES) return e - N_EDGES;          // self loop
  return is64 ? ei[2*(N_EDGES + e)] : ei[N_EDGES + e];
}

// ---------------- CSR build ----------------
__global__ void k_zero2(int* __restrict__ a, int* __restrict__ b, int n){
  int i = blockIdx.x*blockDim.x + threadIdx.x;
  if (i < n){ a[i] = 0; b[i] = 0; }
}

__global__ void k_degree(const int* __restrict__ ei, int* __restrict__ deg,
                         const int* __restrict__ flag){
  int e = blockIdx.x*blockDim.x + threadIdx.x;
  if (e >= ET) return;
  int is64 = *flag;
  int d = edge_dst(ei, e, is64);
  atomicAdd(&deg[d], 1);
}

// ---- 3-stage scan ----
__global__ void k_scan_part(const int* __restrict__ deg, int* __restrict__ loc,
                            int* __restrict__ part){
  __shared__ int lds[256];
  int t = threadIdx.x, i = blockIdx.x*256 + t;
  int v = (i < N_NODES) ? deg[i] : 0;
  lds[t] = v;
  __syncthreads();
  for (int off = 1; off < 256; off <<= 1){
    int x = (t >= off) ? lds[t - off] : 0;
    __syncthreads();
    lds[t] += x;
    __syncthreads();
  }
  if (i < N_NODES) loc[i] = lds[t] - v;          // local exclusive
  if (t == 255) part[blockIdx.x] = lds[255];
}

__global__ void k_scan_carry(int* __restrict__ part, int* __restrict__ carry){
  __shared__ int lds[256];
  int t = threadIdx.x;
  int v = (t < SCAN_NB) ? part[t] : 0;
  lds[t] = v;
  __syncthreads();
  for (int off = 1; off < 256; off <<= 1){
    int x = (t >= off) ? lds[t - off] : 0;
    __syncthreads();
    lds[t] += x;
    __syncthreads();
  }
  if (t < SCAN_NB) carry[t] = lds[t] - v;        // exclusive over blocks
}

__global__ void k_scan_add(const int* __restrict__ loc, const int* __restrict__ carry,
                           int* __restrict__ row_ptr){
  int i = blockIdx.x*blockDim.x + threadIdx.x;
  if (i < N_NODES) row_ptr[i] = loc[i] + carry[i >> 8];
  if (i == 0) row_ptr[N_NODES] = ET;
}

__global__ void k_fill(const int* __restrict__ ei, const int* __restrict__ row_ptr,
                       int* __restrict__ cnt, int* __restrict__ col,
                       const int* __restrict__ flag){
  int e = blockIdx.x*blockDim.x + threadIdx.x;
  if (e >= ET) return;
  int is64 = *flag;
  int s = edge_src(ei, e, is64);
  int d = edge_dst(ei, e, is64);
  int pos = atomicAdd(&cnt[d], 1);
  col[row_ptr[d] + pos] = s;
}

// ---------------- weight prep ----------------
// wtilde[h*128+k] = sum_d W2[k, h*64+d] * att[h,d]
__global__ void k_wtilde(const float* __restrict__ W2, const float* __restrict__ as2,
                         const float* __restrict__ ad2,
                         float* __restrict__ ws2, float* __restrict__ wd2){
  int t = blockIdx.x*blockDim.x + threadIdx.x;
  if (t >= 1024) return;
  int k = t >> 3, h = t & 7;
  float s = 0.f, d = 0.f;
  for (int dd = 0; dd < 64; dd++){
    float w = W2[k*512 + h*64 + dd];
    s += w * as2[h*64 + dd];
    d += w * ad2[h*64 + dd];
  }
  ws2[h*128 + k] = s;
  wd2[h*128 + k] = d;
}

// W1 fp16 B-fragments for mfma_f32_16x16x32_f16: K=128 (kt 0..3), Ncols=128 (nt 0..7)
__global__ void k_w1pack(const float* __restrict__ W1, _Float16* __restrict__ Bp1){
  int t = blockIdx.x*blockDim.x + threadIdx.x;
  if (t >= 16384) return;
  int j = t & 7, lane = (t >> 3) & 63, nt = (t >> 9) & 7, kt = t >> 12;
  int k = kt*32 + (lane >> 4)*8 + j;
  int c = nt*16 + (lane & 15);
  Bp1[t] = (_Float16)W1[k*128 + c];
}

// W2 fp16 B-fragments, 0.125 (head mean) folded; K=1024 (kt 0..31), Ncols=64 (nt 0..3)
__global__ void k_w2pack(const float* __restrict__ W2, _Float16* __restrict__ Bp){
  int t = blockIdx.x*blockDim.x + threadIdx.x;
  if (t >= 65536) return;
  int j = t & 7, lane = (t >> 3) & 63, nt = (t >> 9) & 3, kt = t >> 11;
  int k = kt*32 + (lane >> 4)*8 + j;
  int c = nt*16 + (lane & 15);
  int h = k >> 7, kk = k & 127;
  Bp[t] = (_Float16)(0.125f * W2[kk*512 + h*64 + c]);
}

// ---------------- layer 1 GEMM via MFMA: h1[N,128] = x @ W1 (fp16 out) ----------------
__global__ void __launch_bounds__(256) k_gemm1_mfma(
    const float* __restrict__ x, const _Float16* __restrict__ Bp1,
    _Float16* __restrict__ h1){
  int tid = threadIdx.x;
  int lane = tid & 63, wv = tid >> 6;
  int n0 = blockIdx.x*64 + wv*16;
  int rowA = n0 + (lane & 15);
  int koff = (lane >> 4)*8;
  const float* xr = x + (size_t)rowA*128 + koff;
  f32x4 acc[8];
  #pragma unroll
  for (int i = 0; i < 8; i++) acc[i] = (f32x4){0.f,0.f,0.f,0.f};
  bool inb = (rowA < N_NODES);
  #pragma unroll
  for (int kt = 0; kt < 4; kt++){
    half8 af;
    if (inb){
      float4 a0 = *(const float4*)(xr + kt*32);
      float4 a1 = *(const float4*)(xr + kt*32 + 4);
      af = (half8){(_Float16)a0.x,(_Float16)a0.y,(_Float16)a0.z,(_Float16)a0.w,
                   (_Float16)a1.x,(_Float16)a1.y,(_Float16)a1.z,(_Float16)a1.w};
    } else {
      af = (half8){0,0,0,0,0,0,0,0};
    }
    #pragma unroll
    for (int nt = 0; nt < 8; nt++){
      half8 bf = *(const half8*)(Bp1 + (((kt*8 + nt)*64 + lane) << 3));
      acc[nt] = __builtin_amdgcn_mfma_f32_16x16x32_f16(af, bf, acc[nt], 0, 0, 0);
    }
  }
  int r0 = n0 + (lane >> 4)*4;     // C/D: col=lane&15, row=(lane>>4)*4+reg  [m89]
  #pragma unroll
  for (int nt = 0; nt < 8; nt++){
    int c = nt*16 + (lane & 15);
    #pragma unroll
    for (int r = 0; r < 4; r++){
      int n = r0 + r;
      if (n < N_NODES) h1[(size_t)n*128 + c] = (_Float16)acc[nt][r];
    }
  }
}

// ---- alpha logits, layer 1: als1[n,h] = sum_{d<16} h1[n,h*16+d]*as1[h*16+d] ----
__global__ void k_alpha1(const _Float16* __restrict__ h1, const float* __restrict__ as1,
                         const float* __restrict__ ad1,
                         float* __restrict__ als, float* __restrict__ ald){
  int t = blockIdx.x*blockDim.x + threadIdx.x;
  if (t >= N_NODES*8) return;
  int n = t >> 3, hh = t & 7;
  const half2v* hp = (const half2v*)(h1 + (size_t)n*128 + hh*16);
  float s = 0.f, d = 0.f;
  #pragma unroll
  for (int i = 0; i < 8; i++){
    half2v v = hp[i];
    float vx = (float)v.x, vy = (float)v.y;
    s += vx*as1[hh*16 + 2*i] + vy*as1[hh*16 + 2*i + 1];
    d += vx*ad1[hh*16 + 2*i] + vy*ad1[hh*16 + 2*i + 1];
  }
  als[t] = s; ald[t] = d;
}

// ---- alpha logits, layer 2: als2[n,h] = sum_{k<128} hr[n,k]*ws2[h*128+k] ----
__global__ void k_alpha2(const _Float16* __restrict__ hr, const float* __restrict__ ws2,
                         const float* __restrict__ wd2,
                         float* __restrict__ als, float* __restrict__ ald){
  int t = blockIdx.x*blockDim.x + threadIdx.x;
  if (t >= N_NODES*8) return;
  int n = t >> 3, hh = t & 7;
  const half2v* hp = (const half2v*)(hr + (size_t)n*128);
  float s = 0.f, d = 0.f;
  #pragma unroll 16
  for (int i = 0; i < 64; i++){
    half2v v = hp[i];
    float vx = (float)v.x, vy = (float)v.y;
    s += vx*ws2[hh*128 + 2*i] + vy*ws2[hh*128 + 2*i + 1];
    d += vx*wd2[hh*128 + 2*i] + vy*wd2[hh*128 + 2*i + 1];
  }
  als[t] = s; ald[t] = d;
}

// ------ edge softmax: gather pass (online m,l) + coalesced normalize to fp16 ------
__global__ void k_attn(const float* __restrict__ als, const float* __restrict__ ald,
                       const int* __restrict__ row_ptr, const int* __restrict__ col,
                       float* __restrict__ ewl, _Float16* __restrict__ ewh){
  int gid = blockIdx.x*blockDim.x + threadIdx.x;
  int n = gid >> 6;
  int lane = threadIdx.x & 63;
  if (n >= N_NODES) return;
  int beg = row_ptr[n], end = row_ptr[n+1];
  int items = (end - beg) * 8;        // (edge, head) pairs
  int h = lane & 7;                   // fixed head class per lane
  float ad = ald[n*8 + h];
  float* ewb = ewl + (size_t)beg*8;
  float m = -1e30f, l = 0.f;
  int it = lane;
  for (; it + 192 < items; it += 256){
    int s0 = col[beg + (it >> 3)];
    int s1 = col[beg + ((it + 64) >> 3)];
    int s2 = col[beg + ((it + 128) >> 3)];
    int s3 = col[beg + ((it + 192) >> 3)];
    float a0 = als[s0*8 + h] + ad; a0 = (a0 > 0.f) ? a0 : 0.2f*a0;
    float a1 = als[s1*8 + h] + ad; a1 = (a1 > 0.f) ? a1 : 0.2f*a1;
    float a2 = als[s2*8 + h] + ad; a2 = (a2 > 0.f) ? a2 : 0.2f*a2;
    float a3 = als[s3*8 + h] + ad; a3 = (a3 > 0.f) ? a3 : 0.2f*a3;
    ewb[it] = a0; ewb[it + 64] = a1; ewb[it + 128] = a2; ewb[it + 192] = a3;
    float nm = fmaxf(m, fmaxf(fmaxf(a0, a1), fmaxf(a2, a3)));
    l = l*__expf(m - nm) + __expf(a0 - nm) + __expf(a1 - nm)
        + __expf(a2 - nm) + __expf(a3 - nm);
    m = nm;
  }
  for (; it < items; it += 64){
    int s = col[beg + (it >> 3)];
    float a = als[s*8 + h] + ad; a = (a > 0.f) ? a : 0.2f*a;
    ewb[it] = a;
    float nm = fmaxf(m, a);
    l = l*__expf(m - nm) + __expf(a - nm);
    m = nm;
  }
  // combine (m,l) across lanes of same head (stride 8)
  #pragma unroll
  for (int off = 8; off < 64; off <<= 1){
    float mo = __shfl_xor(m, off, 64);
    float lo = __shfl_xor(l, off, 64);
    float nm = fmaxf(m, mo);
    l = l*__expf(m - nm) + lo*__expf(mo - nm);
    m = nm;
  }
  float inv = 1.f / (l + 1e-16f);
  // pass 2: coalesced normalize fp32 logits -> fp16 weights
  _Float16* ewo = ewh + (size_t)beg*8;
  for (int it2 = lane; it2 < items; it2 += 64){
    float e = ewb[it2];
    ewo[it2] = (_Float16)(__expf(e - m) * inv);
  }
}

// ------- layer-1 aggregation: concat heads, +b1, relu -> hr fp16 -------
// lane owns channels {2*lane, 2*lane+1}; head = lane>>3; unroll 8 for MLP
__global__ void k_agg1(const _Float16* __restrict__ h1, const _Float16* __restrict__ ewh,
                       const int* __restrict__ row_ptr, const int* __restrict__ col,
                       const float* __restrict__ bias, _Float16* __restrict__ hr){
  int gid = blockIdx.x*blockDim.x + threadIdx.x;
  int n = gid >> 6;
  int lane = threadIdx.x & 63;
  if (n >= N_NODES) return;
  int beg = row_ptr[n], end = row_ptr[n+1];
  int hh0 = lane >> 3;
  const half2v* h2p = (const half2v*)h1;
  float ax = 0.f, ay = 0.f;
  int j = beg;
  for (; j + 7 < end; j += 8){
    int s[8]; float w[8]; half2v v[8];
    #pragma unroll
    for (int u = 0; u < 8; u++) s[u] = col[j + u];
    #pragma unroll
    for (int u = 0; u < 8; u++) w[u] = (float)ewh[(size_t)(j + u)*8 + hh0];
    #pragma unroll
    for (int u = 0; u < 8; u++) v[u] = h2p[(size_t)s[u]*64 + lane];
    #pragma unroll
    for (int u = 0; u < 8; u++){ ax += w[u]*(float)v[u].x; ay += w[u]*(float)v[u].y; }
  }
  for (; j < end; j++){
    int s = col[j];
    float w = (float)ewh[(size_t)j*8 + hh0];
    half2v v = h2p[(size_t)s*64 + lane];
    ax += w*(float)v.x; ay += w*(float)v.y;
  }
  float2 bb = ((const float2*)bias)[lane];
  float o0 = fmaxf(ax + bb.x, 0.f);
  float o1 = fmaxf(ay + bb.y, 0.f);
  half2v oo; oo.x = (_Float16)o0; oo.y = (_Float16)o1;
  ((half2v*)hr)[(size_t)n*64 + lane] = oo;
}

// ------- layer-2 gather: per-head weighted sums of hr -> fp16 agg[N,1024] -------
__global__ void k_agg2n(const _Float16* __restrict__ hr, const _Float16* __restrict__ ewh,
                        const int* __restrict__ row_ptr, const int* __restrict__ col,
                        unsigned int* __restrict__ aggb){
  int gid = blockIdx.x*blockDim.x + threadIdx.x;
  int n = gid >> 6;
  int lane = threadIdx.x & 63;
  if (n >= N_NODES) return;
  int beg = row_ptr[n], end = row_ptr[n+1];
  const half2v* hr2 = (const half2v*)hr;
  float accx[8], accy[8];
  #pragma unroll
  for (int i = 0; i < 8; i++){ accx[i] = 0.f; accy[i] = 0.f; }
  int j = beg;
  for (; j + 3 < end; j += 4){
    int s0 = col[j], s1 = col[j+1], s2 = col[j+2], s3 = col[j+3];
    half2v v0 = hr2[(size_t)s0*64 + lane];
    half2v v1 = hr2[(size_t)s1*64 + lane];
    half2v v2 = hr2[(size_t)s2*64 + lane];
    half2v v3 = hr2[(size_t)s3*64 + lane];
    half8 w0 = *(const half8*)(ewh + (size_t)j*8);
    half8 w1 = *(const half8*)(ewh + (size_t)(j+1)*8);
    half8 w2 = *(const half8*)(ewh + (size_t)(j+2)*8);
    half8 w3 = *(const half8*)(ewh + (size_t)(j+3)*8);
    float v0x=(float)v0.x, v0y=(float)v0.y, v1x=(float)v1.x, v1y=(float)v1.y;
    float v2x=(float)v2.x, v2y=(float)v2.y, v3x=(float)v3.x, v3y=(float)v3.y;
    #pragma unroll
    for (int i = 0; i < 8; i++){
      accx[i] += (float)w0[i]*v0x + (float)w1[i]*v1x + (float)w2[i]*v2x + (float)w3[i]*v3x;
      accy[i] += (float)w0[i]*v0y + (float)w1[i]*v1y + (float)w2[i]*v2y + (float)w3[i]*v3y;
    }
  }
  for (; j < end; j++){
    int s = col[j];
    half2v v = hr2[(size_t)s*64 + lane];
    half8 w = *(const half8*)(ewh + (size_t)j*8);
    float vx = (float)v.x, vy = (float)v.y;
    #pragma unroll
    for (int i = 0; i < 8; i++){
      accx[i] += (float)w[i]*vx;
      accy[i] += (float)w[i]*vy;
    }
  }
  unsigned int* ar = aggb + (size_t)n*512 + lane;
  #pragma unroll
  for (int i = 0; i < 8; i++){
    half2v pk; pk.x = (_Float16)accx[i]; pk.y = (_Float16)accy[i];
    union { half2v h; unsigned int u; } cv; cv.h = pk;
    ar[i*64] = cv.u;
  }
}

// ------- layer-2 output GEMM via MFMA f16: out = agg[N,1024] @ Wt[1024,64] + b2 -------
__global__ void __launch_bounds__(256) k_gemm_out_mfma(
    const _Float16* __restrict__ aggb, const _Float16* __restrict__ Bp,
    const float* __restrict__ b2, float* __restrict__ outp){
  int tid = threadIdx.x;
  int lane = tid & 63, wv = tid >> 6;
  int n0 = blockIdx.x*64 + wv*16;
  int rowA = n0 + (lane & 15);
  const _Float16* arow = aggb + (size_t)rowA*1024 + (lane >> 4)*8;
  f32x4 acc[4];
  #pragma unroll
  for (int i = 0; i < 4; i++) acc[i] = (f32x4){0.f,0.f,0.f,0.f};
  for (int kt = 0; kt < 32; kt++){
    half8 af = *(const half8*)(arow + kt*32);
    #pragma unroll
    for (int nt = 0; nt < 4; nt++){
      half8 bf = *(const half8*)(Bp + (((kt*4 + nt)*64 + lane) << 3));
      acc[nt] = __builtin_amdgcn_mfma_f32_16x16x32_f16(af, bf, acc[nt], 0, 0, 0);
    }
  }
  int r0 = n0 + (lane >> 4)*4;     // C/D: col=lane&15, row=(lane>>4)*4+reg  [m89]
  #pragma unroll
  for (int nt = 0; nt < 4; nt++){
    int c = nt*16 + (lane & 15);
    float bb = b2[c];
    #pragma unroll
    for (int r = 0; r < 4; r++){
      int n = r0 + r;
      if (n < N_NODES) outp[n*64 + c] = acc[nt][r] + bb;
    }
  }
}

extern "C" void kernel_launch(void* const* d_in, const int* in_sizes, int n_in,
                              void* d_out, int out_size, void* d_ws, size_t ws_size,
                              hipStream_t stream){
  const float* x   = (const float*)d_in[0];
  const int*   ei  = (const int*)d_in[1];
  const float* W1  = (const float*)d_in[2];
  const float* as1 = (const float*)d_in[3];
  const float* ad1 = (const float*)d_in[4];
  const float* b1  = (const float*)d_in[5];
  const float* W2  = (const float*)d_in[6];
  const float* as2 = (const float*)d_in[7];
  const float* ad2 = (const float*)d_in[8];
  const float* b2  = (const float*)d_in[9];
  float* outp = (float*)d_out;

  char* p = (char*)d_ws;
  auto alloc = [&](size_t bytes) -> void* {
    void* r = (void*)p;
    p += (bytes + 255) & ~(size_t)255;
    return r;
  };
  // aggb region (102.5 MB) also hosts h1 (12.8 MB) and ewl (27.2 MB) — both dead
  // before k_agg2n writes aggb.
  unsigned int* aggb = (unsigned int*)alloc((size_t)NPAD*1024*2);
  _Float16* h1  = (_Float16*)aggb;                               // [N,128] fp16
  float*    ewl = (float*)((char*)aggb + ((size_t)N_NODES*128*2 + 4096 & ~(size_t)255));
  _Float16* hr  = (_Float16*)alloc((size_t)N_NODES*128*2);       // [N,128] fp16
  float* als1 = (float*)alloc((size_t)N_NODES*8*4);
  float* ald1 = (float*)alloc((size_t)N_NODES*8*4);
  float* als2 = (float*)alloc((size_t)N_NODES*8*4);
  float* ald2 = (float*)alloc((size_t)N_NODES*8*4);
  _Float16* ewh = (_Float16*)alloc((size_t)ET*8*2);              // fp16 weights
  int* row_ptr = (int*)alloc((size_t)(N_NODES+1)*4);
  int* deg  = (int*)alloc((size_t)N_NODES*4);
  int* cnt  = (int*)alloc((size_t)N_NODES*4);
  int* col  = (int*)alloc((size_t)ET*4);
  int* loc  = (int*)alloc((size_t)N_NODES*4);
  int* part = (int*)alloc(256*4);
  int* carry= (int*)alloc(256*4);
  int* flag = (int*)alloc(256);
  float* ws2 = (float*)alloc(1024*4);
  float* wd2 = (float*)alloc(1024*4);
  _Float16* Bp1 = (_Float16*)alloc((size_t)16384*2);
  _Float16* Bp  = (_Float16*)alloc((size_t)65536*2);

  dim3 b256(256);
  // edge-index layout probe + CSR build
  k_detect<<<1, 64, 0, stream>>>(ei, flag);
  k_zero2<<<(N_NODES+255)/256, b256, 0, stream>>>(deg, cnt, N_NODES);
  k_degree<<<(ET+255)/256, b256, 0, stream>>>(ei, deg, flag);
  k_scan_part<<<SCAN_NB, b256, 0, stream>>>(deg, loc, part);
  k_scan_carry<<<1, b256, 0, stream>>>(part, carry);
  k_scan_add<<<SCAN_NB, b256, 0, stream>>>(loc, carry, row_ptr);
  k_fill<<<(ET+255)/256, b256, 0, stream>>>(ei, row_ptr, cnt, col, flag);
  // weight prep
  k_wtilde<<<4, b256, 0, stream>>>(W2, as2, ad2, ws2, wd2);
  k_w1pack<<<64, b256, 0, stream>>>(W1, Bp1);
  k_w2pack<<<256, b256, 0, stream>>>(W2, Bp);

  int nwave_blocks = (N_NODES*64 + 255)/256;   // one wave per node
  int nh_blocks = (N_NODES*8 + 255)/256;
  // layer 1
  k_gemm1_mfma<<<NPAD/64, b256, 0, stream>>>(x, Bp1, h1);
  k_alpha1<<<nh_blocks, b256, 0, stream>>>(h1, as1, ad1, als1, ald1);
  k_attn<<<nwave_blocks, b256, 0, stream>>>(als1, ald1, row_ptr, col, ewl, ewh);
  k_agg1<<<nwave_blocks, b256, 0, stream>>>(h1, ewh, row_ptr, col, b1, hr);
  // layer 2
  k_alpha2<<<nh_blocks, b256, 0, stream>>>(hr, ws2, wd2, als2, ald2);
  k_attn<<<nwave_blocks, b256, 0, stream>>>(als2, ald2, row_ptr, col, ewl, ewh);
  k_agg2n<<<nwave_blocks, b256, 0, stream>>>(hr, ewh, row_ptr, col, aggb);
  k_gemm_out_mfma<<<NPAD/64, b256, 0, stream>>>((const _Float16*)aggb, Bp, b2, outp);
}

// Round 6
// 441.870 us; speedup vs baseline: 3.0980x; 1.0223x over previous
//
#include <hip/hip_runtime.h>

#define N_NODES 50000
#define N_EDGES 800000
#define ET (N_EDGES + N_NODES)   // 850000 incl. self loops
#define HEADS 8
#define NPAD 50048               // 782 blocks * 64 nodes
#define SCAN_NB 196              // ceil(50000/256)

typedef __attribute__((ext_vector_type(8))) _Float16 half8;
typedef __attribute__((ext_vector_type(2))) _Float16 half2v;
typedef __attribute__((ext_vector_type(4))) float f32x4;

// ---------- edge-index layout detection (int32 vs int64 storage) ----------
__global__ void k_detect(const int* __restrict__ ei, int* __restrict__ flag){
  if (blockIdx.x == 0 && threadIdx.x == 0){
    int zeros = 0;
    for (int i = 0; i < 64; i++){
      if (ei[2*i + 1] == 0) zeros++;
    }
    *flag = (zeros >= 60) ? 1 : 0;   // 1 => int64 little-endian layout
  }
}

__device__ __forceinline__ int edge_src(const int* ei, int e, int is64){
  if (e >= N_EDGES) return e - N_EDGES;          // self loop
  return is64 ? ei[2*e] : ei[e];
}
__device__ __forceinline__ int edge_dst(const int* ei, int e, int is64){
  if (e >= N_EDGES) return e - N_EDGES;          // self loop
  return is64 ? ei[2*(N_EDGES + e)] : ei[N_EDGES + e];
}

// ---------------- CSR build ----------------
__global__ void k_zero2(int* __restrict__ a, int* __restrict__ b, int n){
  int i = blockIdx.x*blockDim.x + threadIdx.x;
  if (i < n){ a[i] = 0; b[i] = 0; }
}

__global__ void k_degree(const int* __restrict__ ei, int* __restrict__ deg,
                         const int* __restrict__ flag){
  int e = blockIdx.x*blockDim.x + threadIdx.x;
  if (e >= ET) return;
  int is64 = *flag;
  int d = edge_dst(ei, e, is64);
  atomicAdd(&deg[d], 1);
}

// ---- 3-stage scan ----
__global__ void k_scan_part(const int* __restrict__ deg, int* __restrict__ loc,
                            int* __restrict__ part){
  __shared__ int lds[256];
  int t = threadIdx.x, i = blockIdx.x*256 + t;
  int v = (i < N_NODES) ? deg[i] : 0;
  lds[t] = v;
  __syncthreads();
  for (int off = 1; off < 256; off <<= 1){
    int x = (t >= off) ? lds[t - off] : 0;
    __syncthreads();
    lds[t] += x;
    __syncthreads();
  }
  if (i < N_NODES) loc[i] = lds[t] - v;          // local exclusive
  if (t == 255) part[blockIdx.x] = lds[255];
}

__global__ void k_scan_carry(int* __restrict__ part, int* __restrict__ carry){
  __shared__ int lds[256];
  int t = threadIdx.x;
  int v = (t < SCAN_NB) ? part[t] : 0;
  lds[t] = v;
  __syncthreads();
  for (int off = 1; off < 256; off <<= 1){
    int x = (t >= off) ? lds[t - off] : 0;
    __syncthreads();
    lds[t] += x;
    __syncthreads();
  }
  if (t < SCAN_NB) carry[t] = lds[t] - v;        // exclusive over blocks
}

__global__ void k_scan_add(const int* __restrict__ loc, const int* __restrict__ carry,
                           int* __restrict__ row_ptr){
  int i = blockIdx.x*blockDim.x + threadIdx.x;
  if (i < N_NODES) row_ptr[i] = loc[i] + carry[i >> 8];
  if (i == 0) row_ptr[N_NODES] = ET;
}

__global__ void k_fill(const int* __restrict__ ei, const int* __restrict__ row_ptr,
                       int* __restrict__ cnt, int* __restrict__ col,
                       const int* __restrict__ flag){
  int e = blockIdx.x*blockDim.x + threadIdx.x;
  if (e >= ET) return;
  int is64 = *flag;
  int s = edge_src(ei, e, is64);
  int d = edge_dst(ei, e, is64);
  int pos = atomicAdd(&cnt[d], 1);
  col[row_ptr[d] + pos] = s;
}

// ---------------- weight prep ----------------
// wtilde[h*128+k] = sum_d W2[k, h*64+d] * att[h,d]
__global__ void k_wtilde(const float* __restrict__ W2, const float* __restrict__ as2,
                         const float* __restrict__ ad2,
                         float* __restrict__ ws2, float* __restrict__ wd2){
  int t = blockIdx.x*blockDim.x + threadIdx.x;
  if (t >= 1024) return;
  int k = t >> 3, h = t & 7;
  float s = 0.f, d = 0.f;
  for (int dd = 0; dd < 64; dd++){
    float w = W2[k*512 + h*64 + dd];
    s += w * as2[h*64 + dd];
    d += w * ad2[h*64 + dd];
  }
  ws2[h*128 + k] = s;
  wd2[h*128 + k] = d;
}

// W1 fp16 B-fragments for mfma_f32_16x16x32_f16: K=128 (kt 0..3), Ncols=128 (nt 0..7)
__global__ void k_w1pack(const float* __restrict__ W1, _Float16* __restrict__ Bp1){
  int t = blockIdx.x*blockDim.x + threadIdx.x;
  if (t >= 16384) return;
  int j = t & 7, lane = (t >> 3) & 63, nt = (t >> 9) & 7, kt = t >> 12;
  int k = kt*32 + (lane >> 4)*8 + j;
  int c = nt*16 + (lane & 15);
  Bp1[t] = (_Float16)W1[k*128 + c];
}

// W2 fp16 B-fragments, 0.125 (head mean) folded; K=1024 (kt 0..31), Ncols=64 (nt 0..3)
__global__ void k_w2pack(const float* __restrict__ W2, _Float16* __restrict__ Bp){
  int t = blockIdx.x*blockDim.x + threadIdx.x;
  if (t >= 65536) return;
  int j = t & 7, lane = (t >> 3) & 63, nt = (t >> 9) & 3, kt = t >> 11;
  int k = kt*32 + (lane >> 4)*8 + j;
  int c = nt*16 + (lane & 15);
  int h = k >> 7, kk = k & 127;
  Bp[t] = (_Float16)(0.125f * W2[kk*512 + h*64 + c]);
}

// ---------------- layer 1 GEMM via MFMA: h1[N,128] = x @ W1 (fp16 out) ----------------
__global__ void __launch_bounds__(256) k_gemm1_mfma(
    const float* __restrict__ x, const _Float16* __restrict__ Bp1,
    _Float16* __restrict__ h1){
  int tid = threadIdx.x;
  int lane = tid & 63, wv = tid >> 6;
  int n0 = blockIdx.x*64 + wv*16;
  int rowA = n0 + (lane & 15);
  int koff = (lane >> 4)*8;
  const float* xr = x + (size_t)rowA*128 + koff;
  f32x4 acc[8];
  #pragma unroll
  for (int i = 0; i < 8; i++) acc[i] = (f32x4){0.f,0.f,0.f,0.f};
  bool inb = (rowA < N_NODES);
  #pragma unroll
  for (int kt = 0; kt < 4; kt++){
    half8 af;
    if (inb){
      float4 a0 = *(const float4*)(xr + kt*32);
      float4 a1 = *(const float4*)(xr + kt*32 + 4);
      af = (half8){(_Float16)a0.x,(_Float16)a0.y,(_Float16)a0.z,(_Float16)a0.w,
                   (_Float16)a1.x,(_Float16)a1.y,(_Float16)a1.z,(_Float16)a1.w};
    } else {
      af = (half8){0,0,0,0,0,0,0,0};
    }
    #pragma unroll
    for (int nt = 0; nt < 8; nt++){
      half8 bf = *(const half8*)(Bp1 + (((kt*8 + nt)*64 + lane) << 3));
      acc[nt] = __builtin_amdgcn_mfma_f32_16x16x32_f16(af, bf, acc[nt], 0, 0, 0);
    }
  }
  int r0 = n0 + (lane >> 4)*4;     // C/D: col=lane&15, row=(lane>>4)*4+reg  [m89]
  #pragma unroll
  for (int nt = 0; nt < 8; nt++){
    int c = nt*16 + (lane & 15);
    #pragma unroll
    for (int r = 0; r < 4; r++){
      int n = r0 + r;
      if (n < N_NODES) h1[(size_t)n*128 + c] = (_Float16)acc[nt][r];
    }
  }
}

// ---- alpha logits, layer 1 ----
__global__ void k_alpha1(const _Float16* __restrict__ h1, const float* __restrict__ as1,
                         const float* __restrict__ ad1,
                         float* __restrict__ als, float* __restrict__ ald){
  int t = blockIdx.x*blockDim.x + threadIdx.x;
  if (t >= N_NODES*8) return;
  int n = t >> 3, hh = t & 7;
  const half2v* hp = (const half2v*)(h1 + (size_t)n*128 + hh*16);
  float s = 0.f, d = 0.f;
  #pragma unroll
  for (int i = 0; i < 8; i++){
    half2v v = hp[i];
    float vx = (float)v.x, vy = (float)v.y;
    s += vx*as1[hh*16 + 2*i] + vy*as1[hh*16 + 2*i + 1];
    d += vx*ad1[hh*16 + 2*i] + vy*ad1[hh*16 + 2*i + 1];
  }
  als[t] = s; ald[t] = d;
}

// ---- alpha logits, layer 2 ----
__global__ void k_alpha2(const _Float16* __restrict__ hr, const float* __restrict__ ws2,
                         const float* __restrict__ wd2,
                         float* __restrict__ als, float* __restrict__ ald){
  int t = blockIdx.x*blockDim.x + threadIdx.x;
  if (t >= N_NODES*8) return;
  int n = t >> 3, hh = t & 7;
  const half2v* hp = (const half2v*)(hr + (size_t)n*128);
  float s = 0.f, d = 0.f;
  #pragma unroll 16
  for (int i = 0; i < 64; i++){
    half2v v = hp[i];
    float vx = (float)v.x, vy = (float)v.y;
    s += vx*ws2[hh*128 + 2*i] + vy*ws2[hh*128 + 2*i + 1];
    d += vx*wd2[hh*128 + 2*i] + vy*wd2[hh*128 + 2*i + 1];
  }
  als[t] = s; ald[t] = d;
}

// ===== merged softmax+aggregation, layer 1 =====
// phase 1: gather logits -> fp16 scratch (coalesced), l = sum(exp) per head
//   (no max subtraction: logits are O(10), exp safe in fp32; ratio identical)
// phase 2: lane owns channels {2L,2L+1}, head hh0=L>>3; w recomputed from logits
__global__ void k_attn_agg1(const _Float16* __restrict__ h1,
    const float* __restrict__ als, const float* __restrict__ ald,
    const int* __restrict__ row_ptr, const int* __restrict__ col,
    const float* __restrict__ bias,
    _Float16* __restrict__ ewl, _Float16* __restrict__ hr){
  int gid = blockIdx.x*blockDim.x + threadIdx.x;
  int n = gid >> 6;
  int lane = threadIdx.x & 63;
  if (n >= N_NODES) return;
  int beg = row_ptr[n], end = row_ptr[n+1];
  int items = (end - beg)*8;
  int h = lane & 7;
  float ad = ald[n*8 + h];
  _Float16* ewb = ewl + (size_t)beg*8;
  float l = 0.f;
  int it = lane;
  for (; it + 192 < items; it += 256){
    int s0 = col[beg + (it >> 3)];
    int s1 = col[beg + ((it + 64) >> 3)];
    int s2 = col[beg + ((it + 128) >> 3)];
    int s3 = col[beg + ((it + 192) >> 3)];
    float a0 = als[s0*8 + h] + ad; a0 = (a0 > 0.f) ? a0 : 0.2f*a0;
    float a1 = als[s1*8 + h] + ad; a1 = (a1 > 0.f) ? a1 : 0.2f*a1;
    float a2 = als[s2*8 + h] + ad; a2 = (a2 > 0.f) ? a2 : 0.2f*a2;
    float a3 = als[s3*8 + h] + ad; a3 = (a3 > 0.f) ? a3 : 0.2f*a3;
    ewb[it] = (_Float16)a0; ewb[it + 64] = (_Float16)a1;
    ewb[it + 128] = (_Float16)a2; ewb[it + 192] = (_Float16)a3;
    l += (__expf(a0) + __expf(a1)) + (__expf(a2) + __expf(a3));
  }
  for (; it < items; it += 64){
    int s = col[beg + (it >> 3)];
    float a = als[s*8 + h] + ad; a = (a > 0.f) ? a : 0.2f*a;
    ewb[it] = (_Float16)a;
    l += __expf(a);
  }
  l += __shfl_xor(l, 8, 64);
  l += __shfl_xor(l, 16, 64);
  l += __shfl_xor(l, 32, 64);
  float inv = 1.f / (l + 1e-16f);
  int hh0 = lane >> 3;
  float invh = __shfl(inv, hh0, 64);   // inv for head hh0 (held by lane hh0)
  // phase 2
  const half2v* h2p = (const half2v*)h1;
  float ax = 0.f, ay = 0.f;
  int j = beg;
  for (; j + 7 < end; j += 8){
    int base = (j - beg)*8 + hh0;
    int s[8]; float w[8]; half2v v[8];
    #pragma unroll
    for (int u = 0; u < 8; u++) s[u] = col[j + u];
    #pragma unroll
    for (int u = 0; u < 8; u++) w[u] = __expf((float)ewb[base + u*8]) * invh;
    #pragma unroll
    for (int u = 0; u < 8; u++) v[u] = h2p[(size_t)s[u]*64 + lane];
    #pragma unroll
    for (int u = 0; u < 8; u++){ ax += w[u]*(float)v[u].x; ay += w[u]*(float)v[u].y; }
  }
  for (; j < end; j++){
    int s = col[j];
    float w = __expf((float)ewb[(j - beg)*8 + hh0]) * invh;
    half2v v = h2p[(size_t)s*64 + lane];
    ax += w*(float)v.x; ay += w*(float)v.y;
  }
  float2 bb = ((const float2*)bias)[lane];
  float o0 = fmaxf(ax + bb.x, 0.f);
  float o1 = fmaxf(ay + bb.y, 0.f);
  half2v oo; oo.x = (_Float16)o0; oo.y = (_Float16)o1;
  ((half2v*)hr)[(size_t)n*64 + lane] = oo;
}

// ===== merged softmax+aggregation, layer 2 =====
// phase 2 lane mapping: head hq=lane&7 (matches lane's own softmax state — no
// shuffles), channels gq*16..gq*16+15 (gq=lane>>3); v_pk_fma_f16 accumulation.
__global__ void k_attn_agg2(const _Float16* __restrict__ hr,
    const float* __restrict__ als, const float* __restrict__ ald,
    const int* __restrict__ row_ptr, const int* __restrict__ col,
    _Float16* __restrict__ ewl, _Float16* __restrict__ aggb){
  int gid = blockIdx.x*blockDim.x + threadIdx.x;
  int n = gid >> 6;
  int lane = threadIdx.x & 63;
  if (n >= N_NODES) return;
  int beg = row_ptr[n], end = row_ptr[n+1];
  int items = (end - beg)*8;
  int h = lane & 7;
  float ad = ald[n*8 + h];
  _Float16* ewb = ewl + (size_t)beg*8;
  float l = 0.f;
  int it = lane;
  for (; it + 192 < items; it += 256){
    int s0 = col[beg + (it >> 3)];
    int s1 = col[beg + ((it + 64) >> 3)];
    int s2 = col[beg + ((it + 128) >> 3)];
    int s3 = col[beg + ((it + 192) >> 3)];
    float a0 = als[s0*8 + h] + ad; a0 = (a0 > 0.f) ? a0 : 0.2f*a0;
    float a1 = als[s1*8 + h] + ad; a1 = (a1 > 0.f) ? a1 : 0.2f*a1;
    float a2 = als[s2*8 + h] + ad; a2 = (a2 > 0.f) ? a2 : 0.2f*a2;
    float a3 = als[s3*8 + h] + ad; a3 = (a3 > 0.f) ? a3 : 0.2f*a3;
    ewb[it] = (_Float16)a0; ewb[it + 64] = (_Float16)a1;
    ewb[it + 128] = (_Float16)a2; ewb[it + 192] = (_Float16)a3;
    l += (__expf(a0) + __expf(a1)) + (__expf(a2) + __expf(a3));
  }
  for (; it < items; it += 64){
    int s = col[beg + (it >> 3)];
    float a = als[s*8 + h] + ad; a = (a > 0.f) ? a : 0.2f*a;
    ewb[it] = (_Float16)a;
    l += __expf(a);
  }
  l += __shfl_xor(l, 8, 64);
  l += __shfl_xor(l, 16, 64);
  l += __shfl_xor(l, 32, 64);
  float inv = 1.f / (l + 1e-16f);   // for head = lane&7 (== hq below)
  // phase 2
  int hq = lane & 7, gq = lane >> 3;
  half2v acc[8];
  #pragma unroll
  for (int i = 0; i < 8; i++) acc[i] = (half2v){(_Float16)0.f, (_Float16)0.f};
  int j = beg;
  for (; j + 3 < end; j += 4){
    int base = (j - beg)*8 + hq;
    int s0 = col[j], s1 = col[j+1], s2 = col[j+2], s3 = col[j+3];
    const _Float16* p0 = hr + (size_t)s0*128 + gq*16;
    const _Float16* p1 = hr + (size_t)s1*128 + gq*16;
    const _Float16* p2 = hr + (size_t)s2*128 + gq*16;
    const _Float16* p3 = hr + (size_t)s3*128 + gq*16;
    half8 va0 = *(const half8*)p0, vb0 = *(const half8*)(p0 + 8);
    half8 va1 = *(const half8*)p1, vb1 = *(const half8*)(p1 + 8);
    half8 va2 = *(const half8*)p2, vb2 = *(const half8*)(p2 + 8);
    half8 va3 = *(const half8*)p3, vb3 = *(const half8*)(p3 + 8);
    float w0 = __expf((float)ewb[base])      * inv;
    float w1 = __expf((float)ewb[base + 8])  * inv;
    float w2 = __expf((float)ewb[base + 16]) * inv;
    float w3 = __expf((float)ewb[base + 24]) * inv;
    _Float16 w0h = (_Float16)w0, w1h = (_Float16)w1;
    _Float16 w2h = (_Float16)w2, w3h = (_Float16)w3;
    half2v w0p = {w0h, w0h}, w1p = {w1h, w1h}, w2p = {w2h, w2h}, w3p = {w3h, w3h};
    #pragma unroll
    for (int k = 0; k < 4; k++){
      acc[k]   += w0p * (half2v){va0[2*k], va0[2*k+1]};
      acc[k+4] += w0p * (half2v){vb0[2*k], vb0[2*k+1]};
      acc[k]   += w1p * (half2v){va1[2*k], va1[2*k+1]};
      acc[k+4] += w1p * (half2v){vb1[2*k], vb1[2*k+1]};
      acc[k]   += w2p * (half2v){va2[2*k], va2[2*k+1]};
      acc[k+4] += w2p * (half2v){vb2[2*k], vb2[2*k+1]};
      acc[k]   += w3p * (half2v){va3[2*k], va3[2*k+1]};
      acc[k+4] += w3p * (half2v){vb3[2*k], vb3[2*k+1]};
    }
  }
  for (; j < end; j++){
    int s = col[j];
    const _Float16* p = hr + (size_t)s*128 + gq*16;
    half8 va = *(const half8*)p, vb = *(const half8*)(p + 8);
    float w = __expf((float)ewb[(j - beg)*8 + hq]) * inv;
    _Float16 wh = (_Float16)w;
    half2v wp = {wh, wh};
    #pragma unroll
    for (int k = 0; k < 4; k++){
      acc[k]   += wp * (half2v){va[2*k], va[2*k+1]};
      acc[k+4] += wp * (half2v){vb[2*k], vb[2*k+1]};
    }
  }
  _Float16* ar = aggb + (size_t)n*1024 + hq*128 + gq*16;
  half8 oa, ob;
  #pragma unroll
  for (int k = 0; k < 4; k++){
    oa[2*k] = acc[k].x;   oa[2*k+1] = acc[k].y;
    ob[2*k] = acc[k+4].x; ob[2*k+1] = acc[k+4].y;
  }
  *(half8*)ar = oa;
  *(half8*)(ar + 8) = ob;
}

// ------- layer-2 output GEMM via MFMA f16: out = agg[N,1024] @ Wt[1024,64] + b2 -------
__global__ void __launch_bounds__(256) k_gemm_out_mfma(
    const _Float16* __restrict__ aggb, const _Float16* __restrict__ Bp,
    const float* __restrict__ b2, float* __restrict__ outp){
  int tid = threadIdx.x;
  int lane = tid & 63, wv = tid >> 6;
  int n0 = blockIdx.x*64 + wv*16;
  int rowA = n0 + (lane & 15);
  const _Float16* arow = aggb + (size_t)rowA*1024 + (lane >> 4)*8;
  f32x4 acc[4];
  #pragma unroll
  for (int i = 0; i < 4; i++) acc[i] = (f32x4){0.f,0.f,0.f,0.f};
  for (int kt = 0; kt < 32; kt++){
    half8 af = *(const half8*)(arow + kt*32);
    #pragma unroll
    for (int nt = 0; nt < 4; nt++){
      half8 bf = *(const half8*)(Bp + (((kt*4 + nt)*64 + lane) << 3));
      acc[nt] = __builtin_amdgcn_mfma_f32_16x16x32_f16(af, bf, acc[nt], 0, 0, 0);
    }
  }
  int r0 = n0 + (lane >> 4)*4;     // C/D: col=lane&15, row=(lane>>4)*4+reg  [m89]
  #pragma unroll
  for (int nt = 0; nt < 4; nt++){
    int c = nt*16 + (lane & 15);
    float bb = b2[c];
    #pragma unroll
    for (int r = 0; r < 4; r++){
      int n = r0 + r;
      if (n < N_NODES) outp[n*64 + c] = acc[nt][r] + bb;
    }
  }
}

extern "C" void kernel_launch(void* const* d_in, const int* in_sizes, int n_in,
                              void* d_out, int out_size, void* d_ws, size_t ws_size,
                              hipStream_t stream){
  const float* x   = (const float*)d_in[0];
  const int*   ei  = (const int*)d_in[1];
  const float* W1  = (const float*)d_in[2];
  const float* as1 = (const float*)d_in[3];
  const float* ad1 = (const float*)d_in[4];
  const float* b1  = (const float*)d_in[5];
  const float* W2  = (const float*)d_in[6];
  const float* as2 = (const float*)d_in[7];
  const float* ad2 = (const float*)d_in[8];
  const float* b2  = (const float*)d_in[9];
  float* outp = (float*)d_out;

  char* p = (char*)d_ws;
  auto alloc = [&](size_t bytes) -> void* {
    void* r = (void*)p;
    p += (bytes + 255) & ~(size_t)255;
    return r;
  };
  // aggb region (102.5 MB) also hosts h1 (12.8 MB) — dead before k_attn_agg2
  // writes aggb. ewl is a separate allocation (live during k_attn_agg2).
  _Float16* aggb = (_Float16*)alloc((size_t)NPAD*1024*2);
  _Float16* h1  = aggb;                                          // [N,128] fp16
  _Float16* hr  = (_Float16*)alloc((size_t)N_NODES*128*2);       // [N,128] fp16
  float* als1 = (float*)alloc((size_t)N_NODES*8*4);
  float* ald1 = (float*)alloc((size_t)N_NODES*8*4);
  float* als2 = (float*)alloc((size_t)N_NODES*8*4);
  float* ald2 = (float*)alloc((size_t)N_NODES*8*4);
  _Float16* ewl = (_Float16*)alloc((size_t)ET*8*2);              // fp16 logits scratch
  int* row_ptr = (int*)alloc((size_t)(N_NODES+1)*4);
  int* deg  = (int*)alloc((size_t)N_NODES*4);
  int* cnt  = (int*)alloc((size_t)N_NODES*4);
  int* col  = (int*)alloc((size_t)ET*4);
  int* loc  = (int*)alloc((size_t)N_NODES*4);
  int* part = (int*)alloc(256*4);
  int* carry= (int*)alloc(256*4);
  int* flag = (int*)alloc(256);
  float* ws2 = (float*)alloc(1024*4);
  float* wd2 = (float*)alloc(1024*4);
  _Float16* Bp1 = (_Float16*)alloc((size_t)16384*2);
  _Float16* Bp  = (_Float16*)alloc((size_t)65536*2);

  dim3 b256(256);
  // edge-index layout probe + CSR build
  k_detect<<<1, 64, 0, stream>>>(ei, flag);
  k_zero2<<<(N_NODES+255)/256, b256, 0, stream>>>(deg, cnt, N_NODES);
  k_degree<<<(ET+255)/256, b256, 0, stream>>>(ei, deg, flag);
  k_scan_part<<<SCAN_NB, b256, 0, stream>>>(deg, loc, part);
  k_scan_carry<<<1, b256, 0, stream>>>(part, carry);
  k_scan_add<<<SCAN_NB, b256, 0, stream>>>(loc, carry, row_ptr);
  k_fill<<<(ET+255)/256, b256, 0, stream>>>(ei, row_ptr, cnt, col, flag);
  // weight prep
  k_wtilde<<<4, b256, 0, stream>>>(W2, as2, ad2, ws2, wd2);
  k_w1pack<<<64, b256, 0, stream>>>(W1, Bp1);
  k_w2pack<<<256, b256, 0, stream>>>(W2, Bp);

  int nwave_blocks = (N_NODES*64 + 255)/256;   // one wave per node
  int nh_blocks = (N_NODES*8 + 255)/256;
  // layer 1
  k_gemm1_mfma<<<NPAD/64, b256, 0, stream>>>(x, Bp1, h1);
  k_alpha1<<<nh_blocks, b256, 0, stream>>>(h1, as1, ad1, als1, ald1);
  k_attn_agg1<<<nwave_blocks, b256, 0, stream>>>(h1, als1, ald1, row_ptr, col,
                                                 b1, ewl, hr);
  // layer 2
  k_alpha2<<<nh_blocks, b256, 0, stream>>>(hr, ws2, wd2, als2, ald2);
  k_attn_agg2<<<nwave_blocks, b256, 0, stream>>>(hr, als2, ald2, row_ptr, col,
                                                 ewl, aggb);
  k_gemm_out_mfma<<<NPAD/64, b256, 0, stream>>>(aggb, Bp, b2, outp);
}